// Round 1
// baseline (10665.082 us; speedup 1.0000x reference)
//
#include <hip/hip_runtime.h>

#define NN 50000
#define EE 800000
#define NETYPE 2

// ---------------- float atomic max via int/uint trick ----------------
__device__ inline void atomicMaxF(float* p, float v) {
  if (v >= 0.0f) atomicMax((int*)p, __float_as_int(v));
  else atomicMin((unsigned int*)p, __float_as_uint(v));
}

// ---------------- generic tiled fp32 GEMM: Z[e] = X @ W[e] ----------------
// grid: (ceil(M/64), NC/64, NE); block 256. K % 32 == 0, NC % 64 == 0.
__global__ __launch_bounds__(256) void gemm_k(
    const float* __restrict__ X, const float* __restrict__ W,
    float* __restrict__ Z, int M, int K, int NC) {
  __shared__ float As[32][68];  // [k][m], padded: stride 68 floats (16B aligned)
  __shared__ float Bs[32][68];  // [k][n]
  const int e = blockIdx.z;
  const float* Wp = W + (size_t)e * K * NC;
  float* Zp = Z + (size_t)e * M * NC;
  const int tid = threadIdx.x;
  const int tx = tid & 15, ty = tid >> 4;
  const int row0 = blockIdx.x * 64, col0 = blockIdx.y * 64;
  float acc[4][4] = {{0.f}};
  for (int k0 = 0; k0 < K; k0 += 32) {
    #pragma unroll
    for (int i = 0; i < 2; i++) {
      int t = tid + i * 256;
      int r = t >> 3, cv = t & 7;
      int rr = row0 + r; if (rr >= M) rr = M - 1;
      float4 v = *(const float4*)(X + (size_t)rr * K + k0 + cv * 4);
      As[cv*4+0][r] = v.x; As[cv*4+1][r] = v.y;
      As[cv*4+2][r] = v.z; As[cv*4+3][r] = v.w;
    }
    #pragma unroll
    for (int i = 0; i < 2; i++) {
      int t = tid + i * 256;
      int r = t >> 4, cv = t & 15;
      float4 v = *(const float4*)(Wp + (size_t)(k0 + r) * NC + col0 + cv * 4);
      *(float4*)&Bs[r][cv*4] = v;
    }
    __syncthreads();
    #pragma unroll
    for (int kk = 0; kk < 32; kk++) {
      float4 a = *(const float4*)&As[kk][ty*4];
      float4 b = *(const float4*)&Bs[kk][tx*4];
      acc[0][0] += a.x*b.x; acc[0][1] += a.x*b.y; acc[0][2] += a.x*b.z; acc[0][3] += a.x*b.w;
      acc[1][0] += a.y*b.x; acc[1][1] += a.y*b.y; acc[1][2] += a.y*b.z; acc[1][3] += a.y*b.w;
      acc[2][0] += a.z*b.x; acc[2][1] += a.z*b.y; acc[2][2] += a.z*b.z; acc[2][3] += a.z*b.w;
      acc[3][0] += a.w*b.x; acc[3][1] += a.w*b.y; acc[3][2] += a.w*b.z; acc[3][3] += a.w*b.w;
    }
    __syncthreads();
  }
  #pragma unroll
  for (int i = 0; i < 4; i++) {
    int r = row0 + ty * 4 + i;
    if (r < M) {
      float4 v = make_float4(acc[i][0], acc[i][1], acc[i][2], acc[i][3]);
      *(float4*)(Zp + (size_t)r * NC + col0 + tx * 4) = v;
    }
  }
}

// ---------------- el/er = rowwise dot of z with a_l / a_r ----------------
// one quad (4 lanes) per (e,n,h) row; el layout [e][n][h]
template<int H, int F>
__global__ __launch_bounds__(256) void dot_alr_k(
    const float* __restrict__ Z, const float* __restrict__ al,
    const float* __restrict__ ar, float* __restrict__ el, float* __restrict__ er) {
  int tid = blockIdx.x * 256 + threadIdx.x;
  int q = tid >> 2, l = tid & 3;
  if (q >= NETYPE * NN * H) return;
  int h = q % H;
  int n = (q / H) % NN;
  int e = q / (H * NN);
  const float* zp  = Z + ((size_t)e * NN + n) * (H * F) + h * F;
  const float* alp = al + (e * H + h) * F;
  const float* arp = ar + (e * H + h) * F;
  float sl = 0.f, sr = 0.f;
  #pragma unroll
  for (int i = l; i < F / 4; i += 4) {
    float4 z4 = *(const float4*)(zp + i * 4);
    float4 a4 = *(const float4*)(alp + i * 4);
    float4 b4 = *(const float4*)(arp + i * 4);
    sl += z4.x*a4.x + z4.y*a4.y + z4.z*a4.z + z4.w*a4.w;
    sr += z4.x*b4.x + z4.y*b4.y + z4.z*b4.z + z4.w*b4.w;
  }
  sl += __shfl_xor(sl, 1); sl += __shfl_xor(sl, 2);
  sr += __shfl_xor(sr, 1); sr += __shfl_xor(sr, 2);
  if (l == 0) { el[q] = sl; er[q] = sr; }
}

// ---------------- edge softmax pass 1: per-dst max ----------------
template<int H>
__global__ __launch_bounds__(256) void edge_max_k(
    const int* __restrict__ src, const int* __restrict__ dst,
    const float* __restrict__ el, const float* __restrict__ er,
    float* __restrict__ m) {
  int i = blockIdx.x * 256 + threadIdx.x;
  if (i >= EE) return;
  int s = src[i], d = dst[i];
  #pragma unroll
  for (int h = 0; h < H; h++) {
    float v = el[s*H+h] + er[d*H+h];
    v = v >= 0.f ? v : 0.2f * v;
    atomicMaxF(&m[d*H+h], v);
  }
}

// ---------------- edge softmax pass 2: per-dst sum of exp ----------------
template<int H>
__global__ __launch_bounds__(256) void edge_den_k(
    const int* __restrict__ src, const int* __restrict__ dst,
    const float* __restrict__ el, const float* __restrict__ er,
    const float* __restrict__ m, float* __restrict__ den) {
  int i = blockIdx.x * 256 + threadIdx.x;
  if (i >= EE) return;
  int s = src[i], d = dst[i];
  #pragma unroll
  for (int h = 0; h < H; h++) {
    float v = el[s*H+h] + er[d*H+h];
    v = v >= 0.f ? v : 0.2f * v;
    unsafeAtomicAdd(&den[d*H+h], __expf(v - m[d*H+h]));
  }
}

// ---------------- edge softmax pass 3: weighted scatter-add ----------------
// H*F/4 lanes per edge, float4 gather of z[src], 4 float atomics into acc[dst]
template<int H, int F>
__global__ __launch_bounds__(256) void edge_scatter_k(
    const int* __restrict__ src, const int* __restrict__ dst,
    const float* __restrict__ el, const float* __restrict__ er,
    const float* __restrict__ m, const float* __restrict__ den,
    const float* __restrict__ z, float* __restrict__ acc,
    const float* __restrict__ fcw, int e) {
  constexpr int G = H * F / 4;       // lanes per edge
  constexpr int EPB = 256 / G;       // edges per block
  int sub = threadIdx.x / G, lane = threadIdx.x % G;
  int edge = blockIdx.x * EPB + sub;
  if (edge >= EE) return;
  int s = src[edge], d = dst[edge];
  constexpr int LPH = F / 4;         // lanes per head
  int h = lane / LPH, f4 = lane % LPH;
  float v = el[s*H+h] + er[d*H+h];
  v = v >= 0.f ? v : 0.2f * v;
  float alpha = __expf(v - m[d*H+h]) / fmaxf(den[d*H+h], 1e-9f);
  if (fcw) alpha *= 0.5f * (fcw[e] + fcw[NETYPE + e]);  // c_e = mean_f fc_w[f,e]
  float4 zv = *(const float4*)(z + (size_t)s * (H*F) + h * F + f4 * 4);
  float* ap = acc + (size_t)d * (H*F) + h * F + f4 * 4;
  unsafeAtomicAdd(ap+0, alpha * zv.x);
  unsafeAtomicAdd(ap+1, alpha * zv.y);
  unsafeAtomicAdd(ap+2, alpha * zv.z);
  unsafeAtomicAdd(ap+3, alpha * zv.w);
}

// ---------------- epilogues ----------------
__global__ __launch_bounds__(256) void finalize_h1_k(
    float* __restrict__ h1, const float* __restrict__ b1) {
  int i = blockIdx.x * 256 + threadIdx.x;
  if (i >= NN * 128) return;
  int f = i & 127;
  h1[i] = 0.5f * h1[i] + 0.5f * (b1[f] + b1[128 + f]);
}

__global__ __launch_bounds__(256) void finalize_h2_k(
    float* __restrict__ h2, const float* __restrict__ b2,
    const float* __restrict__ fcw) {
  int i = blockIdx.x * 256 + threadIdx.x;
  if (i >= NN * 64) return;
  int o = i & 63;
  float c0 = 0.5f * (fcw[0] + fcw[2]);
  float c1 = 0.5f * (fcw[1] + fcw[3]);
  h2[i] += c0 * b2[o] + c1 * b2[64 + o];
}

__global__ __launch_bounds__(256) void colsum_k(
    const float* __restrict__ acc, float* __restrict__ sums) {
  int c = threadIdx.x;                       // column 0..255
  int nper = (NN + gridDim.x - 1) / gridDim.x;
  int n0 = blockIdx.x * nper;
  int n1 = n0 + nper; if (n1 > NN) n1 = NN;
  float s = 0.f;
  for (int n = n0; n < n1; n++) s += acc[(size_t)n * 256 + c];
  unsafeAtomicAdd(&sums[c], s);
}

__global__ __launch_bounds__(256) void center_k(
    float* __restrict__ out, const float* __restrict__ sums) {
  int i = blockIdx.x * 256 + threadIdx.x;
  if (i >= NN * 256) return;
  int c = i & 255;
  out[i] = 0.5f * (out[i] - sums[c] * (1.0f / NN));  // bm cancels under centering
}

// ---------------- host-side launch ----------------
extern "C" void kernel_launch(void* const* d_in, const int* in_sizes, int n_in,
                              void* d_out, int out_size, void* d_ws, size_t ws_size,
                              hipStream_t stream) {
  const float* x   = (const float*)d_in[0];
  const int* src[2] = {(const int*)d_in[1], (const int*)d_in[3]};
  const int* dst[2] = {(const int*)d_in[2], (const int*)d_in[4]};
  const float* W1  = (const float*)d_in[5];
  const float* al1 = (const float*)d_in[6];
  const float* ar1 = (const float*)d_in[7];
  const float* b1  = (const float*)d_in[8];
  const float* W2  = (const float*)d_in[9];
  const float* al2 = (const float*)d_in[10];
  const float* ar2 = (const float*)d_in[11];
  const float* b2  = (const float*)d_in[12];
  const float* Wm  = (const float*)d_in[13];
  const float* alm = (const float*)d_in[14];
  const float* arm = (const float*)d_in[15];
  // d_in[16] = bm: cancels exactly under per-head mean-centering -> unused
  const float* fcw = (const float*)d_in[17];
  float* out = (float*)d_out;

  float* ws   = (float*)d_ws;
  float* z    = ws;                 // up to 2*NN*256 = 25,600,000 floats
  float* h1   = z   + 25600000;     // NN*128 = 6,400,000
  float* h2   = h1  + 6400000;      // NN*64  = 3,200,000
  float* el   = h2  + 3200000;      // 2*NN*4 = 400,000 (max H=4)
  float* er   = el  + 400000;       // 400,000
  float* mx   = er  + 400000;       // 400,000
  float* den  = mx  + 400000;       // 400,000
  float* csum = den + 400000;       // 256

  hipMemsetAsync(h1, 0, (size_t)6400000 * 4, stream);
  hipMemsetAsync(h2, 0, (size_t)3200000 * 4, stream);
  hipMemsetAsync(out, 0, (size_t)NN * 256 * 4, stream);
  hipMemsetAsync(csum, 0, 256 * 4, stream);

  // ================= layer 1: IN=128 -> HID=128, H=1 =================
  gemm_k<<<dim3(782, 2, 2), 256, 0, stream>>>(x, W1, z, NN, 128, 128);
  dot_alr_k<1,128><<<(NETYPE*NN*4 + 255)/256, 256, 0, stream>>>(z, al1, ar1, el, er);
  hipMemsetAsync(mx, 0xFF, (size_t)2*NN*4, stream);   // -NaN bits: acts as -inf for atomicMaxF
  hipMemsetAsync(den, 0, (size_t)2*NN*4, stream);
  for (int e = 0; e < 2; e++)
    edge_max_k<1><<<3125, 256, 0, stream>>>(src[e], dst[e], el + e*NN, er + e*NN, mx + e*NN);
  for (int e = 0; e < 2; e++)
    edge_den_k<1><<<3125, 256, 0, stream>>>(src[e], dst[e], el + e*NN, er + e*NN,
                                            mx + e*NN, den + e*NN);
  for (int e = 0; e < 2; e++)
    edge_scatter_k<1,128><<<EE/8, 256, 0, stream>>>(src[e], dst[e], el + e*NN, er + e*NN,
        mx + e*NN, den + e*NN, z + (size_t)e*NN*128, h1, nullptr, e);
  finalize_h1_k<<<25000, 256, 0, stream>>>(h1, b1);

  // ================= layer 2: HID=128 -> OUT=64, H=1, fc agg =================
  gemm_k<<<dim3(782, 1, 2), 256, 0, stream>>>(h1, W2, z, NN, 128, 64);
  dot_alr_k<1,64><<<(NETYPE*NN*4 + 255)/256, 256, 0, stream>>>(z, al2, ar2, el, er);
  hipMemsetAsync(mx, 0xFF, (size_t)2*NN*4, stream);
  hipMemsetAsync(den, 0, (size_t)2*NN*4, stream);
  for (int e = 0; e < 2; e++)
    edge_max_k<1><<<3125, 256, 0, stream>>>(src[e], dst[e], el + e*NN, er + e*NN, mx + e*NN);
  for (int e = 0; e < 2; e++)
    edge_den_k<1><<<3125, 256, 0, stream>>>(src[e], dst[e], el + e*NN, er + e*NN,
                                            mx + e*NN, den + e*NN);
  for (int e = 0; e < 2; e++)
    edge_scatter_k<1,64><<<EE/16, 256, 0, stream>>>(src[e], dst[e], el + e*NN, er + e*NN,
        mx + e*NN, den + e*NN, z + (size_t)e*NN*64, h2, fcw, e);
  finalize_h2_k<<<12500, 256, 0, stream>>>(h2, b2, fcw);

  // ================= layer MH: OUT=64 -> NH=4 x OUT=64 =================
  gemm_k<<<dim3(782, 4, 2), 256, 0, stream>>>(h2, Wm, z, NN, 64, 256);
  dot_alr_k<4,64><<<(NETYPE*NN*16 + 255)/256, 256, 0, stream>>>(z, alm, arm, el, er);
  hipMemsetAsync(mx, 0xFF, (size_t)2*NN*16, stream);
  hipMemsetAsync(den, 0, (size_t)2*NN*16, stream);
  for (int e = 0; e < 2; e++)
    edge_max_k<4><<<3125, 256, 0, stream>>>(src[e], dst[e], el + e*NN*4, er + e*NN*4, mx + e*NN*4);
  for (int e = 0; e < 2; e++)
    edge_den_k<4><<<3125, 256, 0, stream>>>(src[e], dst[e], el + e*NN*4, er + e*NN*4,
                                            mx + e*NN*4, den + e*NN*4);
  for (int e = 0; e < 2; e++)
    edge_scatter_k<4,64><<<EE/4, 256, 0, stream>>>(src[e], dst[e], el + e*NN*4, er + e*NN*4,
        mx + e*NN*4, den + e*NN*4, z + (size_t)e*NN*256, out, nullptr, e);

  colsum_k<<<256, 256, 0, stream>>>(out, csum);
  center_k<<<50000, 256, 0, stream>>>(out, csum);
}

// Round 2
// 1602.183 us; speedup vs baseline: 6.6566x; 6.6566x over previous
//
#include <hip/hip_runtime.h>

#define NN 50000
#define EE 800000
#define NETYPE 2

// ================= CSR build =================
__global__ __launch_bounds__(256) void deg_k(const int* __restrict__ dst,
                                             int* __restrict__ deg) {
  int i = blockIdx.x * 256 + threadIdx.x;
  if (i < EE) atomicAdd(&deg[dst[i]], 1);
}

// block b: inclusive scan of deg[b*512 .. b*512+511] -> inc, block sum -> bsum[b]
__global__ __launch_bounds__(512) void scan1_k(const int* __restrict__ deg,
                                               int* __restrict__ inc,
                                               int* __restrict__ bsum) {
  __shared__ int s[512];
  int t = threadIdx.x, i = blockIdx.x * 512 + t;
  int v = (i < NN) ? deg[i] : 0;
  s[t] = v; __syncthreads();
  #pragma unroll
  for (int off = 1; off < 512; off <<= 1) {
    int u = (t >= off) ? s[t - off] : 0;
    __syncthreads();
    s[t] += u;
    __syncthreads();
  }
  if (i < NN) inc[i] = s[t];
  if (t == 511) bsum[blockIdx.x] = s[511];
}

// single block: in-place exclusive scan of nb block sums
__global__ __launch_bounds__(128) void scan2_k(int* __restrict__ bsum, int nb) {
  __shared__ int s[128];
  int t = threadIdx.x;
  int v = (t < nb) ? bsum[t] : 0;
  s[t] = v; __syncthreads();
  #pragma unroll
  for (int off = 1; off < 128; off <<= 1) {
    int u = (t >= off) ? s[t - off] : 0;
    __syncthreads();
    s[t] += u;
    __syncthreads();
  }
  if (t < nb) bsum[t] = s[t] - v;
}

__global__ __launch_bounds__(256) void scan3_k(const int* __restrict__ deg,
                                               const int* __restrict__ inc,
                                               const int* __restrict__ bsum,
                                               int* __restrict__ rowptr) {
  int i = blockIdx.x * 256 + threadIdx.x;
  if (i < NN) rowptr[i] = inc[i] - deg[i] + bsum[i >> 9];
  if (i == NN) rowptr[NN] = EE;
}

__global__ __launch_bounds__(256) void csr_scatter_k(
    const int* __restrict__ src, const int* __restrict__ dst,
    const int* __restrict__ rowptr, int* __restrict__ cursor,
    int* __restrict__ csr_src) {
  int i = blockIdx.x * 256 + threadIdx.x;
  if (i >= EE) return;
  int d = dst[i];
  int pos = atomicAdd(&cursor[d], 1);
  csr_src[rowptr[d] + pos] = src[i];
}

// ================= GEMM: Z[e] = X @ W[e], 64x64 tiles fp32 =================
__global__ __launch_bounds__(256) void gemm_k(
    const float* __restrict__ X, const float* __restrict__ W,
    float* __restrict__ Z, int M, int K, int NC) {
  __shared__ float As[32][68];
  __shared__ float Bs[32][68];
  const int e = blockIdx.z;
  const float* Wp = W + (size_t)e * K * NC;
  float* Zp = Z + (size_t)e * M * NC;
  const int tid = threadIdx.x;
  const int tx = tid & 15, ty = tid >> 4;
  const int row0 = blockIdx.x * 64, col0 = blockIdx.y * 64;
  float acc[4][4] = {{0.f}};
  for (int k0 = 0; k0 < K; k0 += 32) {
    #pragma unroll
    for (int i = 0; i < 2; i++) {
      int t = tid + i * 256;
      int r = t >> 3, cv = t & 7;
      int rr = row0 + r; if (rr >= M) rr = M - 1;
      float4 v = *(const float4*)(X + (size_t)rr * K + k0 + cv * 4);
      As[cv*4+0][r] = v.x; As[cv*4+1][r] = v.y;
      As[cv*4+2][r] = v.z; As[cv*4+3][r] = v.w;
    }
    #pragma unroll
    for (int i = 0; i < 2; i++) {
      int t = tid + i * 256;
      int r = t >> 4, cv = t & 15;
      float4 v = *(const float4*)(Wp + (size_t)(k0 + r) * NC + col0 + cv * 4);
      *(float4*)&Bs[r][cv*4] = v;
    }
    __syncthreads();
    #pragma unroll
    for (int kk = 0; kk < 32; kk++) {
      float4 a = *(const float4*)&As[kk][ty*4];
      float4 b = *(const float4*)&Bs[kk][tx*4];
      acc[0][0] += a.x*b.x; acc[0][1] += a.x*b.y; acc[0][2] += a.x*b.z; acc[0][3] += a.x*b.w;
      acc[1][0] += a.y*b.x; acc[1][1] += a.y*b.y; acc[1][2] += a.y*b.z; acc[1][3] += a.y*b.w;
      acc[2][0] += a.z*b.x; acc[2][1] += a.z*b.y; acc[2][2] += a.z*b.z; acc[2][3] += a.z*b.w;
      acc[3][0] += a.w*b.x; acc[3][1] += a.w*b.y; acc[3][2] += a.w*b.z; acc[3][3] += a.w*b.w;
    }
    __syncthreads();
  }
  #pragma unroll
  for (int i = 0; i < 4; i++) {
    int r = row0 + ty * 4 + i;
    if (r < M) {
      float4 v = make_float4(acc[i][0], acc[i][1], acc[i][2], acc[i][3]);
      *(float4*)(Zp + (size_t)r * NC + col0 + tx * 4) = v;
    }
  }
}

// ================= el/er row dots =================
template<int H, int F>
__global__ __launch_bounds__(256) void dot_alr_k(
    const float* __restrict__ Z, const float* __restrict__ al,
    const float* __restrict__ ar, float* __restrict__ el, float* __restrict__ er) {
  int tid = blockIdx.x * 256 + threadIdx.x;
  int q = tid >> 2, l = tid & 3;
  if (q >= NETYPE * NN * H) return;
  int h = q % H;
  int n = (q / H) % NN;
  int e = q / (H * NN);
  const float* zp  = Z + ((size_t)e * NN + n) * (H * F) + h * F;
  const float* alp = al + (e * H + h) * F;
  const float* arp = ar + (e * H + h) * F;
  float sl = 0.f, sr = 0.f;
  #pragma unroll
  for (int i = l; i < F / 4; i += 4) {
    float4 z4 = *(const float4*)(zp + i * 4);
    float4 a4 = *(const float4*)(alp + i * 4);
    float4 b4 = *(const float4*)(arp + i * 4);
    sl += z4.x*a4.x + z4.y*a4.y + z4.z*a4.z + z4.w*a4.w;
    sr += z4.x*b4.x + z4.y*b4.y + z4.z*b4.z + z4.w*b4.w;
  }
  sl += __shfl_xor(sl, 1); sl += __shfl_xor(sl, 2);
  sr += __shfl_xor(sr, 1); sr += __shfl_xor(sr, 2);
  if (l == 0) { el[q] = sl; er[q] = sr; }
}

// ================= per-(e,d,h) softmax max & denominator =================
template<int H>
__global__ __launch_bounds__(256) void maxden_k(
    const int* __restrict__ rp0, const int* __restrict__ cs0,
    const int* __restrict__ rp1, const int* __restrict__ cs1,
    const float* __restrict__ el, const float* __restrict__ er,
    float* __restrict__ m, float* __restrict__ den) {
  int t = blockIdx.x * 256 + threadIdx.x;
  if (t >= 2 * NN * H) return;
  int e = t / (NN * H);
  int r = t % (NN * H);
  int d = r / H, h = r % H;
  const int* rp = e ? rp1 : rp0;
  const int* cs = e ? cs1 : cs0;
  const float* elp = el + (size_t)e * NN * H;
  float erd = er[t];
  int j0 = rp[d], j1 = rp[d + 1];
  float mx = -1e30f;
  for (int j = j0; j < j1; j++) {
    float v = elp[cs[j] * H + h] + erd;
    v = v >= 0.f ? v : 0.2f * v;
    mx = fmaxf(mx, v);
  }
  float sum = 0.f;
  for (int j = j0; j < j1; j++) {
    float v = elp[cs[j] * H + h] + erd;
    v = v >= 0.f ? v : 0.2f * v;
    sum += __expf(v - mx);
  }
  m[t] = mx;
  den[t] = sum;
}

// ================= fused gather-aggregate over both etypes =================
// MODE 0: layer1  (coef 0.5 each, +0.5*(b[0]+b[1]))
// MODE 1: layer2  (coef c_e = 0.5*(fcw[0][e]+fcw[1][e]), +sum_e c_e*b[e])
// MODE 2: layerMH (coef 0.5 each, bias omitted -- cancels under centering)
template<int H, int F, int MODE>
__global__ __launch_bounds__(256) void agg_k(
    const int* __restrict__ rp0, const int* __restrict__ cs0,
    const int* __restrict__ rp1, const int* __restrict__ cs1,
    const float* __restrict__ el, const float* __restrict__ er,
    const float* __restrict__ m, const float* __restrict__ den,
    const float* __restrict__ z, const float* __restrict__ bias,
    const float* __restrict__ fcw, float* __restrict__ out) {
  constexpr int CH = H * F;
  constexpr int DPB = 256 / CH;
  int d = blockIdx.x * DPB + threadIdx.x / CH;
  int t = threadIdx.x % CH;
  int h = t / F;
  float coef0, coef1;
  if (MODE == 1) { coef0 = 0.5f * (fcw[0] + fcw[2]); coef1 = 0.5f * (fcw[1] + fcw[3]); }
  else { coef0 = 0.5f; coef1 = 0.5f; }
  float acc = 0.f;
  #pragma unroll
  for (int e = 0; e < 2; e++) {
    const int* rp = e ? rp1 : rp0;
    const int* cs = e ? cs1 : cs0;
    const float* elp = el + (size_t)e * NN * H;
    int idx = e * NN * H + d * H + h;
    float erd = er[idx];
    float mm = m[idx];
    float inv = 1.f / fmaxf(den[idx], 1e-9f);
    const float* zp = z + (size_t)e * NN * CH;
    int j0 = rp[d], j1 = rp[d + 1];
    float accE = 0.f;
    for (int j = j0; j < j1; j++) {
      int s = cs[j];
      float v = elp[s * H + h] + erd;
      v = v >= 0.f ? v : 0.2f * v;
      float alpha = __expf(v - mm) * inv;
      accE += alpha * zp[(size_t)s * CH + t];
    }
    acc += (e ? coef1 : coef0) * accE;
  }
  if (MODE == 0) acc += 0.5f * (bias[t] + bias[CH + t]);
  else if (MODE == 1) acc += coef0 * bias[t] + coef1 * bias[CH + t];
  out[(size_t)d * CH + t] = acc;
}

// ================= epilogue: per-column mean-centering =================
__global__ __launch_bounds__(256) void colsum_k(
    const float* __restrict__ acc, float* __restrict__ sums) {
  int c = threadIdx.x;
  int nper = (NN + gridDim.x - 1) / gridDim.x;
  int n0 = blockIdx.x * nper;
  int n1 = n0 + nper; if (n1 > NN) n1 = NN;
  float s = 0.f;
  for (int n = n0; n < n1; n++) s += acc[(size_t)n * 256 + c];
  unsafeAtomicAdd(&sums[c], s);
}

__global__ __launch_bounds__(256) void center_k(
    float* __restrict__ out, const float* __restrict__ sums) {
  int i = blockIdx.x * 256 + threadIdx.x;
  if (i >= NN * 256) return;
  int c = i & 255;
  out[i] = out[i] - sums[c] * (1.0f / NN);
}

// ================= host-side launch =================
extern "C" void kernel_launch(void* const* d_in, const int* in_sizes, int n_in,
                              void* d_out, int out_size, void* d_ws, size_t ws_size,
                              hipStream_t stream) {
  const float* x   = (const float*)d_in[0];
  const int* src[2] = {(const int*)d_in[1], (const int*)d_in[3]};
  const int* dst[2] = {(const int*)d_in[2], (const int*)d_in[4]};
  const float* W1  = (const float*)d_in[5];
  const float* al1 = (const float*)d_in[6];
  const float* ar1 = (const float*)d_in[7];
  const float* b1  = (const float*)d_in[8];
  const float* W2  = (const float*)d_in[9];
  const float* al2 = (const float*)d_in[10];
  const float* ar2 = (const float*)d_in[11];
  const float* b2  = (const float*)d_in[12];
  const float* Wm  = (const float*)d_in[13];
  const float* alm = (const float*)d_in[14];
  const float* arm = (const float*)d_in[15];
  // d_in[16] = bm: cancels under per-head mean-centering
  const float* fcw = (const float*)d_in[17];
  float* out = (float*)d_out;

  float* ws   = (float*)d_ws;
  float* z    = ws;                  // 2*NN*256 = 25,600,000 floats max
  float* h1   = z    + 25600000;     // NN*128
  float* h2   = h1   + 6400000;      // NN*64
  float* el   = h2   + 3200000;      // 2*NN*4 max = 400,000
  float* er   = el   + 400000;
  float* mx   = er   + 400000;
  float* den  = mx   + 400000;
  float* csum = den  + 400000;       // 256
  int* rowptr[2], *csr_src[2];
  rowptr[0]  = (int*)(csum + 256);
  rowptr[1]  = rowptr[0] + 50001;
  csr_src[0] = rowptr[1] + 50001;
  csr_src[1] = csr_src[0] + EE;
  // CSR build scratch aliases el/er/mx/den (build finishes before they're used)
  int* deg[2]    = {(int*)el, (int*)el + 50000};
  int* inc[2]    = {(int*)er, (int*)er + 50000};
  int* cursor[2] = {(int*)mx, (int*)mx + 50000};
  int* bsum[2]   = {(int*)den, (int*)den + 128};

  // ---- CSR build (shared by all 3 layers) ----
  hipMemsetAsync(deg[0], 0, 2 * 50000 * sizeof(int), stream);
  hipMemsetAsync(cursor[0], 0, 2 * 50000 * sizeof(int), stream);
  hipMemsetAsync(csum, 0, 256 * sizeof(float), stream);
  for (int e = 0; e < 2; e++) {
    deg_k<<<3125, 256, 0, stream>>>(dst[e], deg[e]);
    scan1_k<<<98, 512, 0, stream>>>(deg[e], inc[e], bsum[e]);
    scan2_k<<<1, 128, 0, stream>>>(bsum[e], 98);
    scan3_k<<<196, 256, 0, stream>>>(deg[e], inc[e], bsum[e], rowptr[e]);
    csr_scatter_k<<<3125, 256, 0, stream>>>(src[e], dst[e], rowptr[e], cursor[e], csr_src[e]);
  }

  // ================= layer 1: IN=128 -> HID=128, H=1 =================
  gemm_k<<<dim3(782, 2, 2), 256, 0, stream>>>(x, W1, z, NN, 128, 128);
  dot_alr_k<1,128><<<1563, 256, 0, stream>>>(z, al1, ar1, el, er);
  maxden_k<1><<<(2*NN + 255)/256, 256, 0, stream>>>(
      rowptr[0], csr_src[0], rowptr[1], csr_src[1], el, er, mx, den);
  agg_k<1,128,0><<<NN/2, 256, 0, stream>>>(
      rowptr[0], csr_src[0], rowptr[1], csr_src[1], el, er, mx, den,
      z, b1, nullptr, h1);

  // ================= layer 2: HID=128 -> OUT=64, H=1, fc agg =================
  gemm_k<<<dim3(782, 1, 2), 256, 0, stream>>>(h1, W2, z, NN, 128, 64);
  dot_alr_k<1,64><<<1563, 256, 0, stream>>>(z, al2, ar2, el, er);
  maxden_k<1><<<(2*NN + 255)/256, 256, 0, stream>>>(
      rowptr[0], csr_src[0], rowptr[1], csr_src[1], el, er, mx, den);
  agg_k<1,64,1><<<NN/4, 256, 0, stream>>>(
      rowptr[0], csr_src[0], rowptr[1], csr_src[1], el, er, mx, den,
      z, b2, fcw, h2);

  // ================= layer MH: OUT=64 -> NH=4 x OUT=64 =================
  gemm_k<<<dim3(782, 4, 2), 256, 0, stream>>>(h2, Wm, z, NN, 64, 256);
  dot_alr_k<4,64><<<6250, 256, 0, stream>>>(z, alm, arm, el, er);
  maxden_k<4><<<(2*NN*4 + 255)/256, 256, 0, stream>>>(
      rowptr[0], csr_src[0], rowptr[1], csr_src[1], el, er, mx, den);
  agg_k<4,64,2><<<NN, 256, 0, stream>>>(
      rowptr[0], csr_src[0], rowptr[1], csr_src[1], el, er, mx, den,
      z, nullptr, nullptr, out);

  colsum_k<<<256, 256, 0, stream>>>(out, csum);
  center_k<<<50000, 256, 0, stream>>>(out, csum);
}

// Round 3
// 999.239 us; speedup vs baseline: 10.6732x; 1.6034x over previous
//
#include <hip/hip_runtime.h>

#define NN 50000
#define EE 800000
#define NETYPE 2

// ================= CSR build =================
__global__ __launch_bounds__(256) void deg_k(const int* __restrict__ dst,
                                             int* __restrict__ deg) {
  int i = blockIdx.x * 256 + threadIdx.x;
  if (i < EE) atomicAdd(&deg[dst[i]], 1);
}

__global__ __launch_bounds__(512) void scan1_k(const int* __restrict__ deg,
                                               int* __restrict__ inc,
                                               int* __restrict__ bsum) {
  __shared__ int s[512];
  int t = threadIdx.x, i = blockIdx.x * 512 + t;
  int v = (i < NN) ? deg[i] : 0;
  s[t] = v; __syncthreads();
  #pragma unroll
  for (int off = 1; off < 512; off <<= 1) {
    int u = (t >= off) ? s[t - off] : 0;
    __syncthreads();
    s[t] += u;
    __syncthreads();
  }
  if (i < NN) inc[i] = s[t];
  if (t == 511) bsum[blockIdx.x] = s[511];
}

__global__ __launch_bounds__(128) void scan2_k(int* __restrict__ bsum, int nb) {
  __shared__ int s[128];
  int t = threadIdx.x;
  int v = (t < nb) ? bsum[t] : 0;
  s[t] = v; __syncthreads();
  #pragma unroll
  for (int off = 1; off < 128; off <<= 1) {
    int u = (t >= off) ? s[t - off] : 0;
    __syncthreads();
    s[t] += u;
    __syncthreads();
  }
  if (t < nb) bsum[t] = s[t] - v;
}

__global__ __launch_bounds__(256) void scan3_k(const int* __restrict__ deg,
                                               const int* __restrict__ inc,
                                               const int* __restrict__ bsum,
                                               int* __restrict__ rowptr) {
  int i = blockIdx.x * 256 + threadIdx.x;
  if (i < NN) rowptr[i] = inc[i] - deg[i] + bsum[i >> 9];
  if (i == NN) rowptr[NN] = EE;
}

__global__ __launch_bounds__(256) void csr_scatter_k(
    const int* __restrict__ src, const int* __restrict__ dst,
    const int* __restrict__ rowptr, int* __restrict__ cursor,
    int* __restrict__ csr_src) {
  int i = blockIdx.x * 256 + threadIdx.x;
  if (i >= EE) return;
  int d = dst[i];
  int pos = atomicAdd(&cursor[d], 1);
  csr_src[rowptr[d] + pos] = src[i];
}

// ================= GEMM: Z[e] = X @ W[e], 64x64 tiles fp32 =================
__global__ __launch_bounds__(256) void gemm_k(
    const float* __restrict__ X, const float* __restrict__ W,
    float* __restrict__ Z, int M, int K, int NC) {
  __shared__ float As[32][68];
  __shared__ float Bs[32][68];
  const int e = blockIdx.z;
  const float* Wp = W + (size_t)e * K * NC;
  float* Zp = Z + (size_t)e * M * NC;
  const int tid = threadIdx.x;
  const int tx = tid & 15, ty = tid >> 4;
  const int row0 = blockIdx.x * 64, col0 = blockIdx.y * 64;
  float acc[4][4] = {{0.f}};
  for (int k0 = 0; k0 < K; k0 += 32) {
    #pragma unroll
    for (int i = 0; i < 2; i++) {
      int t = tid + i * 256;
      int r = t >> 3, cv = t & 7;
      int rr = row0 + r; if (rr >= M) rr = M - 1;
      float4 v = *(const float4*)(X + (size_t)rr * K + k0 + cv * 4);
      As[cv*4+0][r] = v.x; As[cv*4+1][r] = v.y;
      As[cv*4+2][r] = v.z; As[cv*4+3][r] = v.w;
    }
    #pragma unroll
    for (int i = 0; i < 2; i++) {
      int t = tid + i * 256;
      int r = t >> 4, cv = t & 15;
      float4 v = *(const float4*)(Wp + (size_t)(k0 + r) * NC + col0 + cv * 4);
      *(float4*)&Bs[r][cv*4] = v;
    }
    __syncthreads();
    #pragma unroll
    for (int kk = 0; kk < 32; kk++) {
      float4 a = *(const float4*)&As[kk][ty*4];
      float4 b = *(const float4*)&Bs[kk][tx*4];
      acc[0][0] += a.x*b.x; acc[0][1] += a.x*b.y; acc[0][2] += a.x*b.z; acc[0][3] += a.x*b.w;
      acc[1][0] += a.y*b.x; acc[1][1] += a.y*b.y; acc[1][2] += a.y*b.z; acc[1][3] += a.y*b.w;
      acc[2][0] += a.z*b.x; acc[2][1] += a.z*b.y; acc[2][2] += a.z*b.z; acc[2][3] += a.z*b.w;
      acc[3][0] += a.w*b.x; acc[3][1] += a.w*b.y; acc[3][2] += a.w*b.z; acc[3][3] += a.w*b.w;
    }
    __syncthreads();
  }
  #pragma unroll
  for (int i = 0; i < 4; i++) {
    int r = row0 + ty * 4 + i;
    if (r < M) {
      float4 v = make_float4(acc[i][0], acc[i][1], acc[i][2], acc[i][3]);
      *(float4*)(Zp + (size_t)r * NC + col0 + tx * 4) = v;
    }
  }
}

// ================= el/er row dots =================
template<int H, int F>
__global__ __launch_bounds__(256) void dot_alr_k(
    const float* __restrict__ Z, const float* __restrict__ al,
    const float* __restrict__ ar, float* __restrict__ el, float* __restrict__ er) {
  int tid = blockIdx.x * 256 + threadIdx.x;
  int q = tid >> 2, l = tid & 3;
  if (q >= NETYPE * NN * H) return;
  int h = q % H;
  int n = (q / H) % NN;
  int e = q / (H * NN);
  const float* zp  = Z + ((size_t)e * NN + n) * (H * F) + h * F;
  const float* alp = al + (e * H + h) * F;
  const float* arp = ar + (e * H + h) * F;
  float sl = 0.f, sr = 0.f;
  #pragma unroll
  for (int i = l; i < F / 4; i += 4) {
    float4 z4 = *(const float4*)(zp + i * 4);
    float4 a4 = *(const float4*)(alp + i * 4);
    float4 b4 = *(const float4*)(arp + i * 4);
    sl += z4.x*a4.x + z4.y*a4.y + z4.z*a4.z + z4.w*a4.w;
    sr += z4.x*b4.x + z4.y*b4.y + z4.z*b4.z + z4.w*b4.w;
  }
  sl += __shfl_xor(sl, 1); sl += __shfl_xor(sl, 2);
  sr += __shfl_xor(sr, 1); sr += __shfl_xor(sr, 2);
  if (l == 0) { el[q] = sl; er[q] = sr; }
}

// ================= per-(e,d) softmax max & denom, all H heads =================
// one thread per (e,d); el layout [e][n][h] so the H heads are contiguous.
template<int H>
__global__ __launch_bounds__(256) void maxden_k(
    const int* __restrict__ rp0, const int* __restrict__ cs0,
    const int* __restrict__ rp1, const int* __restrict__ cs1,
    const float* __restrict__ el, const float* __restrict__ er,
    float* __restrict__ m, float* __restrict__ den) {
  int t = blockIdx.x * 256 + threadIdx.x;
  if (t >= 2 * NN) return;
  int e = t / NN, d = t % NN;
  const int* rp = e ? rp1 : rp0;
  const int* cs = e ? cs1 : cs0;
  const float* elp = el + (size_t)e * NN * H;
  float erd[H], mx[H], sm[H];
  #pragma unroll
  for (int h = 0; h < H; h++) {
    erd[h] = er[(size_t)e * NN * H + d * H + h];
    mx[h] = -1e30f; sm[h] = 0.f;
  }
  int j0 = rp[d], j1 = rp[d + 1];
  // pass 1: max (unroll x4 for MLP)
  int j = j0;
  for (; j + 4 <= j1; j += 4) {
    int s0 = cs[j], s1 = cs[j+1], s2 = cs[j+2], s3 = cs[j+3];
    #pragma unroll
    for (int h = 0; h < H; h++) {
      float v0 = elp[s0*H+h] + erd[h]; v0 = v0 >= 0.f ? v0 : 0.2f*v0;
      float v1 = elp[s1*H+h] + erd[h]; v1 = v1 >= 0.f ? v1 : 0.2f*v1;
      float v2 = elp[s2*H+h] + erd[h]; v2 = v2 >= 0.f ? v2 : 0.2f*v2;
      float v3 = elp[s3*H+h] + erd[h]; v3 = v3 >= 0.f ? v3 : 0.2f*v3;
      mx[h] = fmaxf(fmaxf(fmaxf(mx[h], v0), fmaxf(v1, v2)), v3);
    }
  }
  for (; j < j1; j++) {
    int s = cs[j];
    #pragma unroll
    for (int h = 0; h < H; h++) {
      float v = elp[s*H+h] + erd[h]; v = v >= 0.f ? v : 0.2f*v;
      mx[h] = fmaxf(mx[h], v);
    }
  }
  // pass 2: sum exp
  j = j0;
  for (; j + 4 <= j1; j += 4) {
    int s0 = cs[j], s1 = cs[j+1], s2 = cs[j+2], s3 = cs[j+3];
    #pragma unroll
    for (int h = 0; h < H; h++) {
      float v0 = elp[s0*H+h] + erd[h]; v0 = v0 >= 0.f ? v0 : 0.2f*v0;
      float v1 = elp[s1*H+h] + erd[h]; v1 = v1 >= 0.f ? v1 : 0.2f*v1;
      float v2 = elp[s2*H+h] + erd[h]; v2 = v2 >= 0.f ? v2 : 0.2f*v2;
      float v3 = elp[s3*H+h] + erd[h]; v3 = v3 >= 0.f ? v3 : 0.2f*v3;
      sm[h] += __expf(v0-mx[h]) + __expf(v1-mx[h]) + __expf(v2-mx[h]) + __expf(v3-mx[h]);
    }
  }
  for (; j < j1; j++) {
    int s = cs[j];
    #pragma unroll
    for (int h = 0; h < H; h++) {
      float v = elp[s*H+h] + erd[h]; v = v >= 0.f ? v : 0.2f*v;
      sm[h] += __expf(v - mx[h]);
    }
  }
  #pragma unroll
  for (int h = 0; h < H; h++) {
    m[(size_t)e * NN * H + d * H + h] = mx[h];
    den[(size_t)e * NN * H + d * H + h] = sm[h];
  }
}

// ================= fused gather-aggregate, float4/lane, unroll x4 =========
// MODE 0: layer1; MODE 1: layer2 (fc coef); MODE 2: layerMH (bias cancels)
template<int H, int F, int MODE>
__global__ __launch_bounds__(256) void agg_k(
    const int* __restrict__ rp0, const int* __restrict__ cs0,
    const int* __restrict__ rp1, const int* __restrict__ cs1,
    const float* __restrict__ el, const float* __restrict__ er,
    const float* __restrict__ m, const float* __restrict__ den,
    const float* __restrict__ z, const float* __restrict__ bias,
    const float* __restrict__ fcw, float* __restrict__ out) {
  constexpr int CH = H * F;
  constexpr int LPD = CH / 4;        // lanes per dst (float4 each)
  constexpr int DPB = 256 / LPD;     // dsts per block
  int d = blockIdx.x * DPB + threadIdx.x / LPD;
  int lane = threadIdx.x % LPD;
  int c0 = lane * 4;                  // first channel of this lane
  int h = c0 / F;
  float coef0, coef1;
  if (MODE == 1) { coef0 = 0.5f * (fcw[0] + fcw[2]); coef1 = 0.5f * (fcw[1] + fcw[3]); }
  else { coef0 = 0.5f; coef1 = 0.5f; }
  float4 acc = make_float4(0.f, 0.f, 0.f, 0.f);
  #pragma unroll
  for (int e = 0; e < 2; e++) {
    const int* rp = e ? rp1 : rp0;
    const int* cs = e ? cs1 : cs0;
    const float* elp = el + (size_t)e * NN * H;
    int idx = e * NN * H + d * H + h;
    float erd = er[idx];
    float mm = m[idx];
    float inv = 1.f / fmaxf(den[idx], 1e-9f);
    const float* zp = z + (size_t)e * NN * CH;
    int j0 = rp[d], j1 = rp[d + 1];
    float4 accE = make_float4(0.f, 0.f, 0.f, 0.f);
    int j = j0;
    for (; j + 4 <= j1; j += 4) {
      int s0 = cs[j], s1 = cs[j+1], s2 = cs[j+2], s3 = cs[j+3];
      float e0 = elp[s0*H+h], e1 = elp[s1*H+h], e2 = elp[s2*H+h], e3 = elp[s3*H+h];
      float4 z0 = *(const float4*)(zp + (size_t)s0 * CH + c0);
      float4 z1 = *(const float4*)(zp + (size_t)s1 * CH + c0);
      float4 z2 = *(const float4*)(zp + (size_t)s2 * CH + c0);
      float4 z3 = *(const float4*)(zp + (size_t)s3 * CH + c0);
      float v0 = e0 + erd; v0 = v0 >= 0.f ? v0 : 0.2f*v0;
      float v1 = e1 + erd; v1 = v1 >= 0.f ? v1 : 0.2f*v1;
      float v2 = e2 + erd; v2 = v2 >= 0.f ? v2 : 0.2f*v2;
      float v3 = e3 + erd; v3 = v3 >= 0.f ? v3 : 0.2f*v3;
      float a0 = __expf(v0 - mm) * inv;
      float a1 = __expf(v1 - mm) * inv;
      float a2 = __expf(v2 - mm) * inv;
      float a3 = __expf(v3 - mm) * inv;
      accE.x += a0*z0.x + a1*z1.x + a2*z2.x + a3*z3.x;
      accE.y += a0*z0.y + a1*z1.y + a2*z2.y + a3*z3.y;
      accE.z += a0*z0.z + a1*z1.z + a2*z2.z + a3*z3.z;
      accE.w += a0*z0.w + a1*z1.w + a2*z2.w + a3*z3.w;
    }
    for (; j < j1; j++) {
      int s = cs[j];
      float v = elp[s*H+h] + erd;
      v = v >= 0.f ? v : 0.2f * v;
      float a = __expf(v - mm) * inv;
      float4 zv = *(const float4*)(zp + (size_t)s * CH + c0);
      accE.x += a*zv.x; accE.y += a*zv.y; accE.z += a*zv.z; accE.w += a*zv.w;
    }
    float c = e ? coef1 : coef0;
    acc.x += c*accE.x; acc.y += c*accE.y; acc.z += c*accE.z; acc.w += c*accE.w;
  }
  if (MODE == 0) {
    acc.x += 0.5f*(bias[c0+0] + bias[CH+c0+0]);
    acc.y += 0.5f*(bias[c0+1] + bias[CH+c0+1]);
    acc.z += 0.5f*(bias[c0+2] + bias[CH+c0+2]);
    acc.w += 0.5f*(bias[c0+3] + bias[CH+c0+3]);
  } else if (MODE == 1) {
    acc.x += coef0*bias[c0+0] + coef1*bias[CH+c0+0];
    acc.y += coef0*bias[c0+1] + coef1*bias[CH+c0+1];
    acc.z += coef0*bias[c0+2] + coef1*bias[CH+c0+2];
    acc.w += coef0*bias[c0+3] + coef1*bias[CH+c0+3];
  }
  *(float4*)(out + (size_t)d * CH + c0) = acc;
}

// ================= epilogue: per-column mean-centering =================
__global__ __launch_bounds__(256) void colsum_k(
    const float* __restrict__ acc, float* __restrict__ sums) {
  int c = threadIdx.x;
  int nper = (NN + gridDim.x - 1) / gridDim.x;
  int n0 = blockIdx.x * nper;
  int n1 = n0 + nper; if (n1 > NN) n1 = NN;
  float s = 0.f;
  for (int n = n0; n < n1; n++) s += acc[(size_t)n * 256 + c];
  unsafeAtomicAdd(&sums[c], s);
}

__global__ __launch_bounds__(256) void center_k(
    float* __restrict__ out, const float* __restrict__ sums) {
  int i = blockIdx.x * 256 + threadIdx.x;
  if (i >= NN * 256) return;
  int c = i & 255;
  out[i] = out[i] - sums[c] * (1.0f / NN);
}

// ================= host-side launch =================
extern "C" void kernel_launch(void* const* d_in, const int* in_sizes, int n_in,
                              void* d_out, int out_size, void* d_ws, size_t ws_size,
                              hipStream_t stream) {
  const float* x   = (const float*)d_in[0];
  const int* src[2] = {(const int*)d_in[1], (const int*)d_in[3]};
  const int* dst[2] = {(const int*)d_in[2], (const int*)d_in[4]};
  const float* W1  = (const float*)d_in[5];
  const float* al1 = (const float*)d_in[6];
  const float* ar1 = (const float*)d_in[7];
  const float* b1  = (const float*)d_in[8];
  const float* W2  = (const float*)d_in[9];
  const float* al2 = (const float*)d_in[10];
  const float* ar2 = (const float*)d_in[11];
  const float* b2  = (const float*)d_in[12];
  const float* Wm  = (const float*)d_in[13];
  const float* alm = (const float*)d_in[14];
  const float* arm = (const float*)d_in[15];
  // d_in[16] = bm: cancels under per-head mean-centering
  const float* fcw = (const float*)d_in[17];
  float* out = (float*)d_out;

  float* ws   = (float*)d_ws;
  float* z    = ws;                  // 2*NN*256 = 25,600,000 floats max
  float* h1   = z    + 25600000;     // NN*128
  float* h2   = h1   + 6400000;      // NN*64
  float* el   = h2   + 3200000;      // 2*NN*4 max = 400,000
  float* er   = el   + 400000;
  float* mx   = er   + 400000;
  float* den  = mx   + 400000;
  float* csum = den  + 400000;       // 256
  int* rowptr[2], *csr_src[2];
  rowptr[0]  = (int*)(csum + 256);
  rowptr[1]  = rowptr[0] + 50001;
  csr_src[0] = rowptr[1] + 50001;
  csr_src[1] = csr_src[0] + EE;
  // CSR build scratch aliases el/er/mx/den (build finishes before they're used)
  int* deg[2]    = {(int*)el, (int*)el + 50000};
  int* inc[2]    = {(int*)er, (int*)er + 50000};
  int* cursor[2] = {(int*)mx, (int*)mx + 50000};
  int* bsum[2]   = {(int*)den, (int*)den + 128};

  // ---- CSR build (shared by all 3 layers) ----
  hipMemsetAsync(deg[0], 0, 2 * 50000 * sizeof(int), stream);
  hipMemsetAsync(cursor[0], 0, 2 * 50000 * sizeof(int), stream);
  hipMemsetAsync(csum, 0, 256 * sizeof(float), stream);
  for (int e = 0; e < 2; e++) {
    deg_k<<<3125, 256, 0, stream>>>(dst[e], deg[e]);
    scan1_k<<<98, 512, 0, stream>>>(deg[e], inc[e], bsum[e]);
    scan2_k<<<1, 128, 0, stream>>>(bsum[e], 98);
    scan3_k<<<196, 256, 0, stream>>>(deg[e], inc[e], bsum[e], rowptr[e]);
    csr_scatter_k<<<3125, 256, 0, stream>>>(src[e], dst[e], rowptr[e], cursor[e], csr_src[e]);
  }

  // ================= layer 1: IN=128 -> HID=128, H=1 =================
  gemm_k<<<dim3(782, 2, 2), 256, 0, stream>>>(x, W1, z, NN, 128, 128);
  dot_alr_k<1,128><<<1563, 256, 0, stream>>>(z, al1, ar1, el, er);
  maxden_k<1><<<(2*NN + 255)/256, 256, 0, stream>>>(
      rowptr[0], csr_src[0], rowptr[1], csr_src[1], el, er, mx, den);
  agg_k<1,128,0><<<NN/8, 256, 0, stream>>>(
      rowptr[0], csr_src[0], rowptr[1], csr_src[1], el, er, mx, den,
      z, b1, nullptr, h1);

  // ================= layer 2: HID=128 -> OUT=64, H=1, fc agg =================
  gemm_k<<<dim3(782, 1, 2), 256, 0, stream>>>(h1, W2, z, NN, 128, 64);
  dot_alr_k<1,64><<<1563, 256, 0, stream>>>(z, al2, ar2, el, er);
  maxden_k<1><<<(2*NN + 255)/256, 256, 0, stream>>>(
      rowptr[0], csr_src[0], rowptr[1], csr_src[1], el, er, mx, den);
  agg_k<1,64,1><<<NN/16, 256, 0, stream>>>(
      rowptr[0], csr_src[0], rowptr[1], csr_src[1], el, er, mx, den,
      z, b2, fcw, h2);

  // ================= layer MH: OUT=64 -> NH=4 x OUT=64 =================
  gemm_k<<<dim3(782, 4, 2), 256, 0, stream>>>(h2, Wm, z, NN, 64, 256);
  dot_alr_k<4,64><<<6250, 256, 0, stream>>>(z, alm, arm, el, er);
  maxden_k<4><<<(2*NN + 255)/256, 256, 0, stream>>>(
      rowptr[0], csr_src[0], rowptr[1], csr_src[1], el, er, mx, den);
  agg_k<4,64,2><<<NN/4, 256, 0, stream>>>(
      rowptr[0], csr_src[0], rowptr[1], csr_src[1], el, er, mx, den,
      z, nullptr, nullptr, out);

  colsum_k<<<256, 256, 0, stream>>>(out, csum);
  center_k<<<50000, 256, 0, stream>>>(out, csum);
}

// Round 4
// 855.763 us; speedup vs baseline: 12.4627x; 1.1677x over previous
//
#include <hip/hip_runtime.h>

#define NN 50000
#define EE 800000
#define NETYPE 2

// ================= CSR build =================
__global__ __launch_bounds__(256) void deg_k(const int* __restrict__ dst,
                                             int* __restrict__ deg) {
  int i = blockIdx.x * 256 + threadIdx.x;
  if (i < EE) atomicAdd(&deg[dst[i]], 1);
}

__global__ __launch_bounds__(512) void scan1_k(const int* __restrict__ deg,
                                               int* __restrict__ inc,
                                               int* __restrict__ bsum) {
  __shared__ int s[512];
  int t = threadIdx.x, i = blockIdx.x * 512 + t;
  int v = (i < NN) ? deg[i] : 0;
  s[t] = v; __syncthreads();
  #pragma unroll
  for (int off = 1; off < 512; off <<= 1) {
    int u = (t >= off) ? s[t - off] : 0;
    __syncthreads();
    s[t] += u;
    __syncthreads();
  }
  if (i < NN) inc[i] = s[t];
  if (t == 511) bsum[blockIdx.x] = s[511];
}

__global__ __launch_bounds__(128) void scan2_k(int* __restrict__ bsum, int nb) {
  __shared__ int s[128];
  int t = threadIdx.x;
  int v = (t < nb) ? bsum[t] : 0;
  s[t] = v; __syncthreads();
  #pragma unroll
  for (int off = 1; off < 128; off <<= 1) {
    int u = (t >= off) ? s[t - off] : 0;
    __syncthreads();
    s[t] += u;
    __syncthreads();
  }
  if (t < nb) bsum[t] = s[t] - v;
}

__global__ __launch_bounds__(256) void scan3_k(const int* __restrict__ deg,
                                               const int* __restrict__ inc,
                                               const int* __restrict__ bsum,
                                               int* __restrict__ rowptr) {
  int i = blockIdx.x * 256 + threadIdx.x;
  if (i < NN) rowptr[i] = inc[i] - deg[i] + bsum[i >> 9];
  if (i == NN) rowptr[NN] = EE;
}

__global__ __launch_bounds__(256) void csr_scatter_k(
    const int* __restrict__ src, const int* __restrict__ dst,
    const int* __restrict__ rowptr, int* __restrict__ cursor,
    int* __restrict__ csr_src) {
  int i = blockIdx.x * 256 + threadIdx.x;
  if (i >= EE) return;
  int d = dst[i];
  int pos = atomicAdd(&cursor[d], 1);
  csr_src[rowptr[d] + pos] = src[i];
}

// ================= GEMM: Z[e] = X @ W[e], 64x64 tiles fp32 =================
__global__ __launch_bounds__(256) void gemm_k(
    const float* __restrict__ X, const float* __restrict__ W,
    float* __restrict__ Z, int M, int K, int NC) {
  __shared__ float As[32][68];
  __shared__ float Bs[32][68];
  const int e = blockIdx.z;
  const float* Wp = W + (size_t)e * K * NC;
  float* Zp = Z + (size_t)e * M * NC;
  const int tid = threadIdx.x;
  const int tx = tid & 15, ty = tid >> 4;
  const int row0 = blockIdx.x * 64, col0 = blockIdx.y * 64;
  float acc[4][4] = {{0.f}};
  for (int k0 = 0; k0 < K; k0 += 32) {
    #pragma unroll
    for (int i = 0; i < 2; i++) {
      int t = tid + i * 256;
      int r = t >> 3, cv = t & 7;
      int rr = row0 + r; if (rr >= M) rr = M - 1;
      float4 v = *(const float4*)(X + (size_t)rr * K + k0 + cv * 4);
      As[cv*4+0][r] = v.x; As[cv*4+1][r] = v.y;
      As[cv*4+2][r] = v.z; As[cv*4+3][r] = v.w;
    }
    #pragma unroll
    for (int i = 0; i < 2; i++) {
      int t = tid + i * 256;
      int r = t >> 4, cv = t & 15;
      float4 v = *(const float4*)(Wp + (size_t)(k0 + r) * NC + col0 + cv * 4);
      *(float4*)&Bs[r][cv*4] = v;
    }
    __syncthreads();
    #pragma unroll
    for (int kk = 0; kk < 32; kk++) {
      float4 a = *(const float4*)&As[kk][ty*4];
      float4 b = *(const float4*)&Bs[kk][tx*4];
      acc[0][0] += a.x*b.x; acc[0][1] += a.x*b.y; acc[0][2] += a.x*b.z; acc[0][3] += a.x*b.w;
      acc[1][0] += a.y*b.x; acc[1][1] += a.y*b.y; acc[1][2] += a.y*b.z; acc[1][3] += a.y*b.w;
      acc[2][0] += a.z*b.x; acc[2][1] += a.z*b.y; acc[2][2] += a.z*b.z; acc[2][3] += a.z*b.w;
      acc[3][0] += a.w*b.x; acc[3][1] += a.w*b.y; acc[3][2] += a.w*b.z; acc[3][3] += a.w*b.w;
    }
    __syncthreads();
  }
  #pragma unroll
  for (int i = 0; i < 4; i++) {
    int r = row0 + ty * 4 + i;
    if (r < M) {
      float4 v = make_float4(acc[i][0], acc[i][1], acc[i][2], acc[i][3]);
      *(float4*)(Zp + (size_t)r * NC + col0 + tx * 4) = v;
    }
  }
}

// ================= el/er row dots (layers 1,2; H=1) =================
template<int H, int F>
__global__ __launch_bounds__(256) void dot_alr_k(
    const float* __restrict__ Z, const float* __restrict__ al,
    const float* __restrict__ ar, float* __restrict__ el, float* __restrict__ er) {
  int tid = blockIdx.x * 256 + threadIdx.x;
  int q = tid >> 2, l = tid & 3;
  if (q >= NETYPE * NN * H) return;
  int h = q % H;
  int n = (q / H) % NN;
  int e = q / (H * NN);
  const float* zp  = Z + ((size_t)e * NN + n) * (H * F) + h * F;
  const float* alp = al + (e * H + h) * F;
  const float* arp = ar + (e * H + h) * F;
  float sl = 0.f, sr = 0.f;
  #pragma unroll
  for (int i = l; i < F / 4; i += 4) {
    float4 z4 = *(const float4*)(zp + i * 4);
    float4 a4 = *(const float4*)(alp + i * 4);
    float4 b4 = *(const float4*)(arp + i * 4);
    sl += z4.x*a4.x + z4.y*a4.y + z4.z*a4.z + z4.w*a4.w;
    sr += z4.x*b4.x + z4.y*b4.y + z4.z*b4.z + z4.w*b4.w;
  }
  sl += __shfl_xor(sl, 1); sl += __shfl_xor(sl, 2);
  sr += __shfl_xor(sr, 1); sr += __shfl_xor(sr, 2);
  if (l == 0) { el[q] = sl; er[q] = sr; }
}

// ================= per-(e,d) softmax max & denom (H=1 layers) =================
__global__ __launch_bounds__(256) void maxden1_k(
    const int* __restrict__ rp0, const int* __restrict__ cs0,
    const int* __restrict__ rp1, const int* __restrict__ cs1,
    const float* __restrict__ el, const float* __restrict__ er,
    float* __restrict__ m, float* __restrict__ den) {
  int t = blockIdx.x * 256 + threadIdx.x;
  if (t >= 2 * NN) return;
  int e = t / NN, d = t % NN;
  const int* rp = e ? rp1 : rp0;
  const int* cs = e ? cs1 : cs0;
  const float* elp = el + (size_t)e * NN;
  float erd = er[t];
  int j0 = rp[d], j1 = rp[d + 1];
  float mx = -1e30f;
  int j = j0;
  for (; j + 4 <= j1; j += 4) {
    float v0 = elp[cs[j]] + erd;   v0 = v0 >= 0.f ? v0 : 0.2f*v0;
    float v1 = elp[cs[j+1]] + erd; v1 = v1 >= 0.f ? v1 : 0.2f*v1;
    float v2 = elp[cs[j+2]] + erd; v2 = v2 >= 0.f ? v2 : 0.2f*v2;
    float v3 = elp[cs[j+3]] + erd; v3 = v3 >= 0.f ? v3 : 0.2f*v3;
    mx = fmaxf(fmaxf(fmaxf(mx, v0), fmaxf(v1, v2)), v3);
  }
  for (; j < j1; j++) {
    float v = elp[cs[j]] + erd; v = v >= 0.f ? v : 0.2f*v;
    mx = fmaxf(mx, v);
  }
  float sm = 0.f;
  j = j0;
  for (; j + 4 <= j1; j += 4) {
    float v0 = elp[cs[j]] + erd;   v0 = v0 >= 0.f ? v0 : 0.2f*v0;
    float v1 = elp[cs[j+1]] + erd; v1 = v1 >= 0.f ? v1 : 0.2f*v1;
    float v2 = elp[cs[j+2]] + erd; v2 = v2 >= 0.f ? v2 : 0.2f*v2;
    float v3 = elp[cs[j+3]] + erd; v3 = v3 >= 0.f ? v3 : 0.2f*v3;
    sm += __expf(v0-mx) + __expf(v1-mx) + __expf(v2-mx) + __expf(v3-mx);
  }
  for (; j < j1; j++) {
    float v = elp[cs[j]] + erd; v = v >= 0.f ? v : 0.2f*v;
    sm += __expf(v - mx);
  }
  m[t] = mx;
  den[t] = sm;
}

// ================= fused gather-aggregate (layers 1,2; H=1) =================
// MODE 0: layer1 (+0.5*(b0+b1)); MODE 1: layer2 (fc coef + coef*bias)
template<int F, int MODE>
__global__ __launch_bounds__(256) void agg_k(
    const int* __restrict__ rp0, const int* __restrict__ cs0,
    const int* __restrict__ rp1, const int* __restrict__ cs1,
    const float* __restrict__ el, const float* __restrict__ er,
    const float* __restrict__ m, const float* __restrict__ den,
    const float* __restrict__ z, const float* __restrict__ bias,
    const float* __restrict__ fcw, float* __restrict__ out) {
  constexpr int LPD = F / 4;
  constexpr int DPB = 256 / LPD;
  int d = blockIdx.x * DPB + threadIdx.x / LPD;
  int lane = threadIdx.x % LPD;
  int c0 = lane * 4;
  float coef0, coef1;
  if (MODE == 1) { coef0 = 0.5f * (fcw[0] + fcw[2]); coef1 = 0.5f * (fcw[1] + fcw[3]); }
  else { coef0 = 0.5f; coef1 = 0.5f; }
  float4 acc = make_float4(0.f, 0.f, 0.f, 0.f);
  #pragma unroll
  for (int e = 0; e < 2; e++) {
    const int* rp = e ? rp1 : rp0;
    const int* cs = e ? cs1 : cs0;
    const float* elp = el + (size_t)e * NN;
    int idx = e * NN + d;
    float erd = er[idx];
    float mm = m[idx];
    float inv = 1.f / fmaxf(den[idx], 1e-9f);
    const float* zp = z + (size_t)e * NN * F;
    int j0 = rp[d], j1 = rp[d + 1];
    float4 accE = make_float4(0.f, 0.f, 0.f, 0.f);
    int j = j0;
    for (; j + 4 <= j1; j += 4) {
      int s0 = cs[j], s1 = cs[j+1], s2 = cs[j+2], s3 = cs[j+3];
      float e0 = elp[s0], e1 = elp[s1], e2 = elp[s2], e3 = elp[s3];
      float4 z0 = *(const float4*)(zp + (size_t)s0 * F + c0);
      float4 z1 = *(const float4*)(zp + (size_t)s1 * F + c0);
      float4 z2 = *(const float4*)(zp + (size_t)s2 * F + c0);
      float4 z3 = *(const float4*)(zp + (size_t)s3 * F + c0);
      float v0 = e0 + erd; v0 = v0 >= 0.f ? v0 : 0.2f*v0;
      float v1 = e1 + erd; v1 = v1 >= 0.f ? v1 : 0.2f*v1;
      float v2 = e2 + erd; v2 = v2 >= 0.f ? v2 : 0.2f*v2;
      float v3 = e3 + erd; v3 = v3 >= 0.f ? v3 : 0.2f*v3;
      float a0 = __expf(v0 - mm) * inv;
      float a1 = __expf(v1 - mm) * inv;
      float a2 = __expf(v2 - mm) * inv;
      float a3 = __expf(v3 - mm) * inv;
      accE.x += a0*z0.x + a1*z1.x + a2*z2.x + a3*z3.x;
      accE.y += a0*z0.y + a1*z1.y + a2*z2.y + a3*z3.y;
      accE.z += a0*z0.z + a1*z1.z + a2*z2.z + a3*z3.z;
      accE.w += a0*z0.w + a1*z1.w + a2*z2.w + a3*z3.w;
    }
    for (; j < j1; j++) {
      int s = cs[j];
      float v = elp[s] + erd;
      v = v >= 0.f ? v : 0.2f * v;
      float a = __expf(v - mm) * inv;
      float4 zv = *(const float4*)(zp + (size_t)s * F + c0);
      accE.x += a*zv.x; accE.y += a*zv.y; accE.z += a*zv.z; accE.w += a*zv.w;
    }
    float c = e ? coef1 : coef0;
    acc.x += c*accE.x; acc.y += c*accE.y; acc.z += c*accE.z; acc.w += c*accE.w;
  }
  if (MODE == 0) {
    acc.x += 0.5f*(bias[c0+0] + bias[F+c0+0]);
    acc.y += 0.5f*(bias[c0+1] + bias[F+c0+1]);
    acc.z += 0.5f*(bias[c0+2] + bias[F+c0+2]);
    acc.w += 0.5f*(bias[c0+3] + bias[F+c0+3]);
  } else {
    acc.x += coef0*bias[c0+0] + coef1*bias[F+c0+0];
    acc.y += coef0*bias[c0+1] + coef1*bias[F+c0+1];
    acc.z += coef0*bias[c0+2] + coef1*bias[F+c0+2];
    acc.w += coef0*bias[c0+3] + coef1*bias[F+c0+3];
  }
  *(float4*)(out + (size_t)d * F + c0) = acc;
}

// ================= MH layer: fold a_l/a_r through Wm =================
// wl[e][h][k] = sum_f Wm[e][k][h*64+f] * alm[e][h][f]   (k = 0..63)
__global__ __launch_bounds__(512) void wlm_k(
    const float* __restrict__ Wm, const float* __restrict__ alm,
    const float* __restrict__ arm, float* __restrict__ wl, float* __restrict__ wr) {
  int t = threadIdx.x;           // 512 = 2*4*64
  int k = t & 63, h = (t >> 6) & 3, e = t >> 8;
  const float* wmp = Wm + ((size_t)e * 64 + k) * 256 + h * 64;
  const float* alp = alm + (e * 4 + h) * 64;
  const float* arp = arm + (e * 4 + h) * 64;
  float sl = 0.f, sr = 0.f;
  for (int f = 0; f < 64; f++) { float w = wmp[f]; sl += w * alp[f]; sr += w * arp[f]; }
  wl[t] = sl; wr[t] = sr;
}

// elm[e][n][h] = h2[n] . wl[e][h];  erm likewise. 16 lanes per (e,n).
__global__ __launch_bounds__(256) void dotm_k(
    const float* __restrict__ h2, const float* __restrict__ wl,
    const float* __restrict__ wr, float* __restrict__ el, float* __restrict__ er) {
  int g = blockIdx.x * 16 + (threadIdx.x >> 4);
  int lane = threadIdx.x & 15;
  if (g >= 2 * NN) return;
  int e = g / NN, n = g % NN;
  float4 z4 = *(const float4*)(h2 + (size_t)n * 64 + lane * 4);
  float p[8];
  #pragma unroll
  for (int h = 0; h < 4; h++) {
    float4 a = *(const float4*)(wl + (e * 4 + h) * 64 + lane * 4);
    float4 b = *(const float4*)(wr + (e * 4 + h) * 64 + lane * 4);
    p[h]     = z4.x*a.x + z4.y*a.y + z4.z*a.z + z4.w*a.w;
    p[4 + h] = z4.x*b.x + z4.y*b.y + z4.z*b.z + z4.w*b.w;
  }
  #pragma unroll
  for (int off = 1; off < 16; off <<= 1) {
    #pragma unroll
    for (int i = 0; i < 8; i++) p[i] += __shfl_xor(p[i], off);
  }
  if (lane == 0) *(float4*)(el + (size_t)g * 4) = make_float4(p[0], p[1], p[2], p[3]);
  if (lane == 8) *(float4*)(er + (size_t)g * 4) = make_float4(p[4], p[5], p[6], p[7]);
}

// per-(e,d): max, den over 4 heads; writes normalized alpha per edge (float4).
__global__ __launch_bounds__(256) void maxden_mh_k(
    const int* __restrict__ rp0, const int* __restrict__ cs0,
    const int* __restrict__ rp1, const int* __restrict__ cs1,
    const float* __restrict__ el, const float* __restrict__ er,
    float* __restrict__ alpha) {
  int t = blockIdx.x * 256 + threadIdx.x;
  if (t >= 2 * NN) return;
  int e = t / NN, d = t % NN;
  const int* rp = e ? rp1 : rp0;
  const int* cs = e ? cs1 : cs0;
  const float* elp = el + (size_t)e * NN * 4;
  float4 er4 = *(const float4*)(er + (size_t)t * 4);
  int j0 = rp[d], j1 = rp[d + 1];
  float4 mx = make_float4(-1e30f, -1e30f, -1e30f, -1e30f);
  for (int j = j0; j < j1; j++) {
    float4 v = *(const float4*)(elp + (size_t)cs[j] * 4);
    v.x += er4.x; v.y += er4.y; v.z += er4.z; v.w += er4.w;
    v.x = v.x >= 0.f ? v.x : 0.2f*v.x; v.y = v.y >= 0.f ? v.y : 0.2f*v.y;
    v.z = v.z >= 0.f ? v.z : 0.2f*v.z; v.w = v.w >= 0.f ? v.w : 0.2f*v.w;
    mx.x = fmaxf(mx.x, v.x); mx.y = fmaxf(mx.y, v.y);
    mx.z = fmaxf(mx.z, v.z); mx.w = fmaxf(mx.w, v.w);
  }
  float4 sm = make_float4(0.f, 0.f, 0.f, 0.f);
  for (int j = j0; j < j1; j++) {
    float4 v = *(const float4*)(elp + (size_t)cs[j] * 4);
    v.x += er4.x; v.y += er4.y; v.z += er4.z; v.w += er4.w;
    v.x = v.x >= 0.f ? v.x : 0.2f*v.x; v.y = v.y >= 0.f ? v.y : 0.2f*v.y;
    v.z = v.z >= 0.f ? v.z : 0.2f*v.z; v.w = v.w >= 0.f ? v.w : 0.2f*v.w;
    sm.x += __expf(v.x - mx.x); sm.y += __expf(v.y - mx.y);
    sm.z += __expf(v.z - mx.z); sm.w += __expf(v.w - mx.w);
  }
  float4 inv = make_float4(1.f / fmaxf(sm.x, 1e-9f), 1.f / fmaxf(sm.y, 1e-9f),
                           1.f / fmaxf(sm.z, 1e-9f), 1.f / fmaxf(sm.w, 1e-9f));
  float* ap = alpha + (size_t)e * EE * 4;
  for (int j = j0; j < j1; j++) {
    float4 v = *(const float4*)(elp + (size_t)cs[j] * 4);
    v.x += er4.x; v.y += er4.y; v.z += er4.z; v.w += er4.w;
    v.x = v.x >= 0.f ? v.x : 0.2f*v.x; v.y = v.y >= 0.f ? v.y : 0.2f*v.y;
    v.z = v.z >= 0.f ? v.z : 0.2f*v.z; v.w = v.w >= 0.f ? v.w : 0.2f*v.w;
    float4 a = make_float4(__expf(v.x - mx.x) * inv.x, __expf(v.y - mx.y) * inv.y,
                           __expf(v.z - mx.z) * inv.z, __expf(v.w - mx.w) * inv.w);
    *(float4*)(ap + (size_t)j * 4) = a;
  }
}

// u[e][h][d][0..63] = sum_j alpha[e][j][h] * h2[src[j]];  16 lanes per dst.
__global__ __launch_bounds__(256) void agg_mh_k(
    const int* __restrict__ rp0, const int* __restrict__ cs0,
    const int* __restrict__ rp1, const int* __restrict__ cs1,
    const float* __restrict__ alpha, const float* __restrict__ h2,
    float* __restrict__ u) {
  int d = blockIdx.x * 16 + (threadIdx.x >> 4);
  int lane = threadIdx.x & 15, c0 = lane * 4;
  #pragma unroll
  for (int e = 0; e < 2; e++) {
    const int* rp = e ? rp1 : rp0;
    const int* cs = e ? cs1 : cs0;
    const float* ap = alpha + (size_t)e * EE * 4;
    float4 a0 = make_float4(0,0,0,0), a1 = make_float4(0,0,0,0);
    float4 a2 = make_float4(0,0,0,0), a3 = make_float4(0,0,0,0);
    int j0 = rp[d], j1 = rp[d + 1];
    int j = j0;
    for (; j + 2 <= j1; j += 2) {
      int sA = cs[j], sB = cs[j+1];
      float4 wA = *(const float4*)(ap + (size_t)j * 4);
      float4 wB = *(const float4*)(ap + (size_t)(j+1) * 4);
      float4 zA = *(const float4*)(h2 + (size_t)sA * 64 + c0);
      float4 zB = *(const float4*)(h2 + (size_t)sB * 64 + c0);
      a0.x += wA.x*zA.x + wB.x*zB.x; a0.y += wA.x*zA.y + wB.x*zB.y;
      a0.z += wA.x*zA.z + wB.x*zB.z; a0.w += wA.x*zA.w + wB.x*zB.w;
      a1.x += wA.y*zA.x + wB.y*zB.x; a1.y += wA.y*zA.y + wB.y*zB.y;
      a1.z += wA.y*zA.z + wB.y*zB.z; a1.w += wA.y*zA.w + wB.y*zB.w;
      a2.x += wA.z*zA.x + wB.z*zB.x; a2.y += wA.z*zA.y + wB.z*zB.y;
      a2.z += wA.z*zA.z + wB.z*zB.z; a2.w += wA.z*zA.w + wB.z*zB.w;
      a3.x += wA.w*zA.x + wB.w*zB.x; a3.y += wA.w*zA.y + wB.w*zB.y;
      a3.z += wA.w*zA.z + wB.w*zB.z; a3.w += wA.w*zA.w + wB.w*zB.w;
    }
    for (; j < j1; j++) {
      int s = cs[j];
      float4 w = *(const float4*)(ap + (size_t)j * 4);
      float4 z = *(const float4*)(h2 + (size_t)s * 64 + c0);
      a0.x += w.x*z.x; a0.y += w.x*z.y; a0.z += w.x*z.z; a0.w += w.x*z.w;
      a1.x += w.y*z.x; a1.y += w.y*z.y; a1.z += w.y*z.z; a1.w += w.y*z.w;
      a2.x += w.z*z.x; a2.y += w.z*z.y; a2.z += w.z*z.z; a2.w += w.z*z.w;
      a3.x += w.w*z.x; a3.y += w.w*z.y; a3.z += w.w*z.z; a3.w += w.w*z.w;
    }
    size_t base = ((size_t)e * 4 * NN + d) * 64 + c0;
    *(float4*)(u + base)                       = a0;
    *(float4*)(u + base + (size_t)NN * 64)     = a1;
    *(float4*)(u + base + (size_t)2 * NN * 64) = a2;
    *(float4*)(u + base + (size_t)3 * NN * 64) = a3;
  }
}

// out[d][h*64+f] = 0.5 * sum_e u[e][h][d][:] @ Wm[e][:, h*64+f]
__global__ __launch_bounds__(256) void out_gemm_k(
    const float* __restrict__ u, const float* __restrict__ Wm,
    float* __restrict__ out) {
  __shared__ float As[32][68];
  __shared__ float Bs[32][68];
  const int h = blockIdx.y;
  const int tid = threadIdx.x;
  const int tx = tid & 15, ty = tid >> 4;
  const int row0 = blockIdx.x * 64;
  float acc[4][4] = {{0.f}};
  for (int e = 0; e < 2; e++) {
    const float* Up = u + (size_t)(e * 4 + h) * NN * 64;
    const float* Wp = Wm + (size_t)e * 64 * 256 + h * 64;
    for (int k0 = 0; k0 < 64; k0 += 32) {
      #pragma unroll
      for (int i = 0; i < 2; i++) {
        int t = tid + i * 256;
        int r = t >> 3, cv = t & 7;
        int rr = row0 + r; if (rr >= NN) rr = NN - 1;
        float4 v = *(const float4*)(Up + (size_t)rr * 64 + k0 + cv * 4);
        As[cv*4+0][r] = v.x; As[cv*4+1][r] = v.y;
        As[cv*4+2][r] = v.z; As[cv*4+3][r] = v.w;
      }
      #pragma unroll
      for (int i = 0; i < 2; i++) {
        int t = tid + i * 256;
        int r = t >> 4, cv = t & 15;
        float4 v = *(const float4*)(Wp + (size_t)(k0 + r) * 256 + cv * 4);
        *(float4*)&Bs[r][cv*4] = v;
      }
      __syncthreads();
      #pragma unroll
      for (int kk = 0; kk < 32; kk++) {
        float4 a = *(const float4*)&As[kk][ty*4];
        float4 b = *(const float4*)&Bs[kk][tx*4];
        acc[0][0] += a.x*b.x; acc[0][1] += a.x*b.y; acc[0][2] += a.x*b.z; acc[0][3] += a.x*b.w;
        acc[1][0] += a.y*b.x; acc[1][1] += a.y*b.y; acc[1][2] += a.y*b.z; acc[1][3] += a.y*b.w;
        acc[2][0] += a.z*b.x; acc[2][1] += a.z*b.y; acc[2][2] += a.z*b.z; acc[2][3] += a.z*b.w;
        acc[3][0] += a.w*b.x; acc[3][1] += a.w*b.y; acc[3][2] += a.w*b.z; acc[3][3] += a.w*b.w;
      }
      __syncthreads();
    }
  }
  #pragma unroll
  for (int i = 0; i < 4; i++) {
    int r = row0 + ty * 4 + i;
    if (r < NN) {
      float4 v = make_float4(0.5f*acc[i][0], 0.5f*acc[i][1], 0.5f*acc[i][2], 0.5f*acc[i][3]);
      *(float4*)(out + (size_t)r * 256 + h * 64 + tx * 4) = v;
    }
  }
}

// ================= epilogue: per-column mean-centering =================
__global__ __launch_bounds__(256) void colsum_k(
    const float* __restrict__ acc, float* __restrict__ sums) {
  int c = threadIdx.x;
  int nper = (NN + gridDim.x - 1) / gridDim.x;
  int n0 = blockIdx.x * nper;
  int n1 = n0 + nper; if (n1 > NN) n1 = NN;
  float s = 0.f;
  for (int n = n0; n < n1; n++) s += acc[(size_t)n * 256 + c];
  unsafeAtomicAdd(&sums[c], s);
}

__global__ __launch_bounds__(256) void center_k(
    float* __restrict__ out, const float* __restrict__ sums) {
  int i = blockIdx.x * 256 + threadIdx.x;
  if (i >= NN * 256) return;
  int c = i & 255;
  out[i] = out[i] - sums[c] * (1.0f / NN);
}

// ================= host-side launch =================
extern "C" void kernel_launch(void* const* d_in, const int* in_sizes, int n_in,
                              void* d_out, int out_size, void* d_ws, size_t ws_size,
                              hipStream_t stream) {
  const float* x   = (const float*)d_in[0];
  const int* src[2] = {(const int*)d_in[1], (const int*)d_in[3]};
  const int* dst[2] = {(const int*)d_in[2], (const int*)d_in[4]};
  const float* W1  = (const float*)d_in[5];
  const float* al1 = (const float*)d_in[6];
  const float* ar1 = (const float*)d_in[7];
  const float* b1  = (const float*)d_in[8];
  const float* W2  = (const float*)d_in[9];
  const float* al2 = (const float*)d_in[10];
  const float* ar2 = (const float*)d_in[11];
  const float* b2  = (const float*)d_in[12];
  const float* Wm  = (const float*)d_in[13];
  const float* alm = (const float*)d_in[14];
  const float* arm = (const float*)d_in[15];
  // d_in[16] = bm: cancels under per-head mean-centering
  const float* fcw = (const float*)d_in[17];
  float* out = (float*)d_out;

  float* ws = (float*)d_ws;
  // region 0..25.6M: z for layers 1/2, then u (2*4*NN*64 = 25.6M) for MH
  float* zu   = ws;
  float* h1   = ws + 25600000;   // 6.4M; reused as alpha (2*EE*4 = 6.4M) in MH
  float* alpha= h1;
  float* h2   = ws + 32000000;   // 3.2M
  float* el   = ws + 35200000;   // 0.4M
  float* er   = ws + 35600000;   // 0.4M
  float* mx   = ws + 36000000;   // 0.4M
  float* den  = ws + 36400000;   // 0.4M
  float* csum = ws + 36800000;   // 256
  float* wlm  = ws + 36800256;   // 512
  float* wrm  = ws + 36800768;   // 512
  int* rowptr[2], *csr_src[2];
  rowptr[0]  = (int*)(ws + 36801280);
  rowptr[1]  = rowptr[0] + 50001;
  csr_src[0] = rowptr[1] + 50001;
  csr_src[1] = csr_src[0] + EE;
  // CSR build scratch aliases el/er/mx/den
  int* deg[2]    = {(int*)el, (int*)el + 50000};
  int* inc[2]    = {(int*)er, (int*)er + 50000};
  int* cursor[2] = {(int*)mx, (int*)mx + 50000};
  int* bsum[2]   = {(int*)den, (int*)den + 128};

  // ---- CSR build ----
  hipMemsetAsync(deg[0], 0, 2 * 50000 * sizeof(int), stream);
  hipMemsetAsync(cursor[0], 0, 2 * 50000 * sizeof(int), stream);
  hipMemsetAsync(csum, 0, 256 * sizeof(float), stream);
  for (int e = 0; e < 2; e++) {
    deg_k<<<3125, 256, 0, stream>>>(dst[e], deg[e]);
    scan1_k<<<98, 512, 0, stream>>>(deg[e], inc[e], bsum[e]);
    scan2_k<<<1, 128, 0, stream>>>(bsum[e], 98);
    scan3_k<<<196, 256, 0, stream>>>(deg[e], inc[e], bsum[e], rowptr[e]);
    csr_scatter_k<<<3125, 256, 0, stream>>>(src[e], dst[e], rowptr[e], cursor[e], csr_src[e]);
  }

  // ================= layer 1: IN=128 -> HID=128 =================
  gemm_k<<<dim3(782, 2, 2), 256, 0, stream>>>(x, W1, zu, NN, 128, 128);
  dot_alr_k<1,128><<<1563, 256, 0, stream>>>(zu, al1, ar1, el, er);
  maxden1_k<<<391, 256, 0, stream>>>(
      rowptr[0], csr_src[0], rowptr[1], csr_src[1], el, er, mx, den);
  agg_k<128,0><<<NN/8, 256, 0, stream>>>(
      rowptr[0], csr_src[0], rowptr[1], csr_src[1], el, er, mx, den,
      zu, b1, nullptr, h1);

  // ================= layer 2: HID=128 -> OUT=64, fc agg =================
  gemm_k<<<dim3(782, 1, 2), 256, 0, stream>>>(h1, W2, zu, NN, 128, 64);
  dot_alr_k<1,64><<<1563, 256, 0, stream>>>(zu, al2, ar2, el, er);
  maxden1_k<<<391, 256, 0, stream>>>(
      rowptr[0], csr_src[0], rowptr[1], csr_src[1], el, er, mx, den);
  agg_k<64,1><<<NN/16, 256, 0, stream>>>(
      rowptr[0], csr_src[0], rowptr[1], csr_src[1], el, er, mx, den,
      zu, b2, fcw, h2);

  // ================= MH layer: gather h2, post-GEMM with Wm =================
  wlm_k<<<1, 512, 0, stream>>>(Wm, alm, arm, wlm, wrm);
  dotm_k<<<6250, 256, 0, stream>>>(h2, wlm, wrm, el, er);
  maxden_mh_k<<<391, 256, 0, stream>>>(
      rowptr[0], csr_src[0], rowptr[1], csr_src[1], el, er, alpha);
  agg_mh_k<<<3125, 256, 0, stream>>>(
      rowptr[0], csr_src[0], rowptr[1], csr_src[1], alpha, h2, zu);
  out_gemm_k<<<dim3(782, 4), 256, 0, stream>>>(zu, Wm, out);

  colsum_k<<<256, 256, 0, stream>>>(out, csum);
  center_k<<<50000, 256, 0, stream>>>(out, csum);
}

// Round 5
// 849.099 us; speedup vs baseline: 12.5605x; 1.0078x over previous
//
#include <hip/hip_runtime.h>

#define NN 50000
#define EE 800000
#define NETYPE 2

// ================= CSR build =================
__global__ __launch_bounds__(256) void deg_k(const int* __restrict__ dst,
                                             int* __restrict__ deg) {
  int i = blockIdx.x * 256 + threadIdx.x;
  if (i < EE) atomicAdd(&deg[dst[i]], 1);
}

__global__ __launch_bounds__(512) void scan1_k(const int* __restrict__ deg,
                                               int* __restrict__ inc,
                                               int* __restrict__ bsum) {
  __shared__ int s[512];
  int t = threadIdx.x, i = blockIdx.x * 512 + t;
  int v = (i < NN) ? deg[i] : 0;
  s[t] = v; __syncthreads();
  #pragma unroll
  for (int off = 1; off < 512; off <<= 1) {
    int u = (t >= off) ? s[t - off] : 0;
    __syncthreads();
    s[t] += u;
    __syncthreads();
  }
  if (i < NN) inc[i] = s[t];
  if (t == 511) bsum[blockIdx.x] = s[511];
}

__global__ __launch_bounds__(128) void scan2_k(int* __restrict__ bsum, int nb) {
  __shared__ int s[128];
  int t = threadIdx.x;
  int v = (t < nb) ? bsum[t] : 0;
  s[t] = v; __syncthreads();
  #pragma unroll
  for (int off = 1; off < 128; off <<= 1) {
    int u = (t >= off) ? s[t - off] : 0;
    __syncthreads();
    s[t] += u;
    __syncthreads();
  }
  if (t < nb) bsum[t] = s[t] - v;
}

__global__ __launch_bounds__(256) void scan3_k(const int* __restrict__ deg,
                                               const int* __restrict__ inc,
                                               const int* __restrict__ bsum,
                                               int* __restrict__ rowptr) {
  int i = blockIdx.x * 256 + threadIdx.x;
  if (i < NN) rowptr[i] = inc[i] - deg[i] + bsum[i >> 9];
  if (i == NN) rowptr[NN] = EE;
}

__global__ __launch_bounds__(256) void csr_scatter_k(
    const int* __restrict__ src, const int* __restrict__ dst,
    const int* __restrict__ rowptr, int* __restrict__ cursor,
    int* __restrict__ csr_src) {
  int i = blockIdx.x * 256 + threadIdx.x;
  if (i >= EE) return;
  int d = dst[i];
  int pos = atomicAdd(&cursor[d], 1);
  csr_src[rowptr[d] + pos] = src[i];
}

// ======== fold a_l/a_r through weights: wl[e] = W[e] @ a[e] ========
__global__ __launch_bounds__(256) void fold_k(
    const float* __restrict__ W1, const float* __restrict__ al1, const float* __restrict__ ar1,
    const float* __restrict__ W2, const float* __restrict__ al2, const float* __restrict__ ar2,
    const float* __restrict__ Wm, const float* __restrict__ alm, const float* __restrict__ arm,
    float* __restrict__ wl1, float* __restrict__ wr1,
    float* __restrict__ wl2, float* __restrict__ wr2,
    float* __restrict__ wlm, float* __restrict__ wrm) {
  int t = blockIdx.x * 256 + threadIdx.x;  // 2048 total
  if (t < 512) {
    int lr = t >> 8, e = (t >> 7) & 1, k = t & 127;
    const float* a = (lr ? ar1 : al1) + e * 128;
    const float* w = W1 + ((size_t)e * 128 + k) * 128;
    float s = 0.f;
    for (int f = 0; f < 128; f++) s += w[f] * a[f];
    (lr ? wr1 : wl1)[e * 128 + k] = s;
  } else if (t < 1024) {
    int u = t - 512;
    int lr = u >> 8, e = (u >> 7) & 1, k = u & 127;
    const float* a = (lr ? ar2 : al2) + e * 64;
    const float* w = W2 + ((size_t)e * 128 + k) * 64;
    float s = 0.f;
    for (int f = 0; f < 64; f++) s += w[f] * a[f];
    (lr ? wr2 : wl2)[e * 128 + k] = s;
  } else {
    int u = t - 1024;
    int lr = u >> 9, e = (u >> 8) & 1, h = (u >> 6) & 3, k = u & 63;
    const float* a = (lr ? arm : alm) + (e * 4 + h) * 64;
    const float* w = Wm + ((size_t)e * 64 + k) * 256 + h * 64;
    float s = 0.f;
    for (int f = 0; f < 64; f++) s += w[f] * a[f];
    (lr ? wrm : wlm)[(e * 4 + h) * 64 + k] = s;
  }
}

// ================= GEMM: Z[e] = X @ W[e], 128xBN tiles fp32 =================
template<int BN>
__global__ __launch_bounds__(256) void gemm_t(
    const float* __restrict__ X, const float* __restrict__ W,
    float* __restrict__ Z, int M, int K) {
  constexpr int NP = BN / 64;
  __shared__ float As[16][132];
  __shared__ float Bs[16][BN + 4];
  const int e = blockIdx.z;
  const float* Wp = W + (size_t)e * K * BN;
  float* Zp = Z + (size_t)e * M * BN;
  const int tid = threadIdx.x;
  const int tx = tid & 15, ty = tid >> 4;
  const int row0 = blockIdx.x * 128;
  float acc[2][NP][16] = {};
  for (int k0 = 0; k0 < K; k0 += 16) {
    #pragma unroll
    for (int i = 0; i < 2; i++) {
      int t = tid + i * 256;
      int r = t >> 2, cv = t & 3;
      int rr = row0 + r; if (rr >= M) rr = M - 1;
      float4 v = *(const float4*)(X + (size_t)rr * K + k0 + cv * 4);
      As[cv*4+0][r] = v.x; As[cv*4+1][r] = v.y;
      As[cv*4+2][r] = v.z; As[cv*4+3][r] = v.w;
    }
    #pragma unroll
    for (int i = 0; i < NP; i++) {
      int t = tid + i * 256;
      int r = t / (BN/4), c = t % (BN/4);
      *(float4*)&Bs[r][c*4] = *(const float4*)(Wp + (size_t)(k0 + r) * BN + c * 4);
    }
    __syncthreads();
    #pragma unroll
    for (int kk = 0; kk < 16; kk++) {
      float4 a[2], b[NP];
      a[0] = *(const float4*)&As[kk][ty*4];
      a[1] = *(const float4*)&As[kk][64 + ty*4];
      #pragma unroll
      for (int p = 0; p < NP; p++) b[p] = *(const float4*)&Bs[kk][p*64 + tx*4];
      #pragma unroll
      for (int rp = 0; rp < 2; rp++) {
        #pragma unroll
        for (int cp = 0; cp < NP; cp++) {
          float* ac = acc[rp][cp];
          float4 av = a[rp], bv = b[cp];
          ac[0]  += av.x*bv.x; ac[1]  += av.x*bv.y; ac[2]  += av.x*bv.z; ac[3]  += av.x*bv.w;
          ac[4]  += av.y*bv.x; ac[5]  += av.y*bv.y; ac[6]  += av.y*bv.z; ac[7]  += av.y*bv.w;
          ac[8]  += av.z*bv.x; ac[9]  += av.z*bv.y; ac[10] += av.z*bv.z; ac[11] += av.z*bv.w;
          ac[12] += av.w*bv.x; ac[13] += av.w*bv.y; ac[14] += av.w*bv.z; ac[15] += av.w*bv.w;
        }
      }
    }
    __syncthreads();
  }
  #pragma unroll
  for (int rp = 0; rp < 2; rp++) {
    #pragma unroll
    for (int cp = 0; cp < NP; cp++) {
      #pragma unroll
      for (int i = 0; i < 4; i++) {
        int r = row0 + rp*64 + ty*4 + i;
        if (r < M) {
          float* ac = acc[rp][cp];
          *(float4*)(Zp + (size_t)r * BN + cp*64 + tx*4) =
              make_float4(ac[i*4+0], ac[i*4+1], ac[i*4+2], ac[i*4+3]);
        }
      }
    }
  }
}

// ================= el/er dots from node features (both etypes) =================
// el[e*NN+n] = X[n] . wl[e]; K = 128
__global__ __launch_bounds__(256) void dot2_k(
    const float* __restrict__ X, const float* __restrict__ wl,
    const float* __restrict__ wr, float* __restrict__ el, float* __restrict__ er) {
  int n = blockIdx.x * 16 + (threadIdx.x >> 4);
  int lane = threadIdx.x & 15;
  if (n >= NN) return;
  float p[4] = {0.f, 0.f, 0.f, 0.f};
  #pragma unroll
  for (int i = 0; i < 2; i++) {
    int c = (lane + i * 16) * 4;
    float4 xv = *(const float4*)(X + (size_t)n * 128 + c);
    #pragma unroll
    for (int e = 0; e < 2; e++) {
      float4 a = *(const float4*)(wl + e * 128 + c);
      float4 b = *(const float4*)(wr + e * 128 + c);
      p[e*2+0] += xv.x*a.x + xv.y*a.y + xv.z*a.z + xv.w*a.w;
      p[e*2+1] += xv.x*b.x + xv.y*b.y + xv.z*b.z + xv.w*b.w;
    }
  }
  #pragma unroll
  for (int off = 1; off < 16; off <<= 1) {
    #pragma unroll
    for (int i = 0; i < 4; i++) p[i] += __shfl_xor(p[i], off);
  }
  if (lane == 0) {
    el[n] = p[0]; er[n] = p[1];
    el[NN + n] = p[2]; er[NN + n] = p[3];
  }
}

// MH: elm[e][n][h] = h2[n] . wlm[e][h]
__global__ __launch_bounds__(256) void dotm_k(
    const float* __restrict__ h2, const float* __restrict__ wl,
    const float* __restrict__ wr, float* __restrict__ el, float* __restrict__ er) {
  int g = blockIdx.x * 16 + (threadIdx.x >> 4);
  int lane = threadIdx.x & 15;
  if (g >= 2 * NN) return;
  int e = g / NN, n = g % NN;
  float4 z4 = *(const float4*)(h2 + (size_t)n * 64 + lane * 4);
  float p[8];
  #pragma unroll
  for (int h = 0; h < 4; h++) {
    float4 a = *(const float4*)(wl + (e * 4 + h) * 64 + lane * 4);
    float4 b = *(const float4*)(wr + (e * 4 + h) * 64 + lane * 4);
    p[h]     = z4.x*a.x + z4.y*a.y + z4.z*a.z + z4.w*a.w;
    p[4 + h] = z4.x*b.x + z4.y*b.y + z4.z*b.z + z4.w*b.w;
  }
  #pragma unroll
  for (int off = 1; off < 16; off <<= 1) {
    #pragma unroll
    for (int i = 0; i < 8; i++) p[i] += __shfl_xor(p[i], off);
  }
  if (lane == 0) *(float4*)(el + (size_t)g * 4) = make_float4(p[0], p[1], p[2], p[3]);
  if (lane == 8) *(float4*)(er + (size_t)g * 4) = make_float4(p[4], p[5], p[6], p[7]);
}

// ===== per-(e,d): den (no max; |v|<~8 so exp is fp32-safe) + write alpha =====
__global__ __launch_bounds__(256) void alpha1_k(
    const int* __restrict__ rp0, const int* __restrict__ cs0,
    const int* __restrict__ rp1, const int* __restrict__ cs1,
    const float* __restrict__ el, const float* __restrict__ er,
    float* __restrict__ alpha) {
  int t = blockIdx.x * 256 + threadIdx.x;
  if (t >= 2 * NN) return;
  int e = t / NN, d = t % NN;
  const int* rp = e ? rp1 : rp0;
  const int* cs = e ? cs1 : cs0;
  const float* elp = el + (size_t)e * NN;
  float erd = er[t];
  int j0 = rp[d], j1 = rp[d + 1];
  float sm = 0.f;
  int j = j0;
  for (; j + 4 <= j1; j += 4) {
    float v0 = elp[cs[j]]   + erd; v0 = v0 >= 0.f ? v0 : 0.2f*v0;
    float v1 = elp[cs[j+1]] + erd; v1 = v1 >= 0.f ? v1 : 0.2f*v1;
    float v2 = elp[cs[j+2]] + erd; v2 = v2 >= 0.f ? v2 : 0.2f*v2;
    float v3 = elp[cs[j+3]] + erd; v3 = v3 >= 0.f ? v3 : 0.2f*v3;
    sm += __expf(v0) + __expf(v1) + __expf(v2) + __expf(v3);
  }
  for (; j < j1; j++) {
    float v = elp[cs[j]] + erd; v = v >= 0.f ? v : 0.2f*v;
    sm += __expf(v);
  }
  float inv = 1.f / fmaxf(sm, 1e-9f);
  float* ap = alpha + (size_t)e * EE;
  j = j0;
  for (; j + 4 <= j1; j += 4) {
    float v0 = elp[cs[j]]   + erd; v0 = v0 >= 0.f ? v0 : 0.2f*v0;
    float v1 = elp[cs[j+1]] + erd; v1 = v1 >= 0.f ? v1 : 0.2f*v1;
    float v2 = elp[cs[j+2]] + erd; v2 = v2 >= 0.f ? v2 : 0.2f*v2;
    float v3 = elp[cs[j+3]] + erd; v3 = v3 >= 0.f ? v3 : 0.2f*v3;
    ap[j]   = __expf(v0) * inv; ap[j+1] = __expf(v1) * inv;
    ap[j+2] = __expf(v2) * inv; ap[j+3] = __expf(v3) * inv;
  }
  for (; j < j1; j++) {
    float v = elp[cs[j]] + erd; v = v >= 0.f ? v : 0.2f*v;
    ap[j] = __expf(v) * inv;
  }
}

// MH variant: 4 heads, float4 alpha per edge
__global__ __launch_bounds__(256) void alpha4_k(
    const int* __restrict__ rp0, const int* __restrict__ cs0,
    const int* __restrict__ rp1, const int* __restrict__ cs1,
    const float* __restrict__ el, const float* __restrict__ er,
    float* __restrict__ alpha) {
  int t = blockIdx.x * 256 + threadIdx.x;
  if (t >= 2 * NN) return;
  int e = t / NN, d = t % NN;
  const int* rp = e ? rp1 : rp0;
  const int* cs = e ? cs1 : cs0;
  const float* elp = el + (size_t)e * NN * 4;
  float4 er4 = *(const float4*)(er + (size_t)t * 4);
  int j0 = rp[d], j1 = rp[d + 1];
  float4 sm = make_float4(0.f, 0.f, 0.f, 0.f);
  for (int j = j0; j < j1; j++) {
    float4 v = *(const float4*)(elp + (size_t)cs[j] * 4);
    v.x += er4.x; v.y += er4.y; v.z += er4.z; v.w += er4.w;
    v.x = v.x >= 0.f ? v.x : 0.2f*v.x; v.y = v.y >= 0.f ? v.y : 0.2f*v.y;
    v.z = v.z >= 0.f ? v.z : 0.2f*v.z; v.w = v.w >= 0.f ? v.w : 0.2f*v.w;
    sm.x += __expf(v.x); sm.y += __expf(v.y);
    sm.z += __expf(v.z); sm.w += __expf(v.w);
  }
  float4 inv = make_float4(1.f / fmaxf(sm.x, 1e-9f), 1.f / fmaxf(sm.y, 1e-9f),
                           1.f / fmaxf(sm.z, 1e-9f), 1.f / fmaxf(sm.w, 1e-9f));
  float* ap = alpha + (size_t)e * EE * 4;
  for (int j = j0; j < j1; j++) {
    float4 v = *(const float4*)(elp + (size_t)cs[j] * 4);
    v.x += er4.x; v.y += er4.y; v.z += er4.z; v.w += er4.w;
    v.x = v.x >= 0.f ? v.x : 0.2f*v.x; v.y = v.y >= 0.f ? v.y : 0.2f*v.y;
    v.z = v.z >= 0.f ? v.z : 0.2f*v.z; v.w = v.w >= 0.f ? v.w : 0.2f*v.w;
    *(float4*)(ap + (size_t)j * 4) =
        make_float4(__expf(v.x) * inv.x, __expf(v.y) * inv.y,
                    __expf(v.z) * inv.z, __expf(v.w) * inv.w);
  }
}

// ========== gather-aggregate with precomputed alpha (layers 1,2) ==========
// MODE 0: layer1 (+0.5*(b0+b1)); MODE 1: layer2 (fc coef + coef*bias)
template<int F, int MODE>
__global__ __launch_bounds__(256) void agg1_k(
    const int* __restrict__ rp0, const int* __restrict__ cs0,
    const int* __restrict__ rp1, const int* __restrict__ cs1,
    const float* __restrict__ alpha, const float* __restrict__ z,
    const float* __restrict__ bias, const float* __restrict__ fcw,
    float* __restrict__ out) {
  constexpr int LPD = F / 4;
  constexpr int DPB = 256 / LPD;
  int d = blockIdx.x * DPB + threadIdx.x / LPD;
  int lane = threadIdx.x % LPD;
  int c0 = lane * 4;
  float coef0, coef1;
  if (MODE == 1) { coef0 = 0.5f * (fcw[0] + fcw[2]); coef1 = 0.5f * (fcw[1] + fcw[3]); }
  else { coef0 = 0.5f; coef1 = 0.5f; }
  float4 acc = make_float4(0.f, 0.f, 0.f, 0.f);
  #pragma unroll
  for (int e = 0; e < 2; e++) {
    const int* rp = e ? rp1 : rp0;
    const int* cs = e ? cs1 : cs0;
    const float* ap = alpha + (size_t)e * EE;
    const float* zp = z + (size_t)e * NN * F;
    int j0 = rp[d], j1 = rp[d + 1];
    float4 accE = make_float4(0.f, 0.f, 0.f, 0.f);
    int j = j0;
    for (; j + 4 <= j1; j += 4) {
      int s0 = cs[j], s1 = cs[j+1], s2 = cs[j+2], s3 = cs[j+3];
      float a0 = ap[j], a1 = ap[j+1], a2 = ap[j+2], a3 = ap[j+3];
      float4 z0 = *(const float4*)(zp + (size_t)s0 * F + c0);
      float4 z1 = *(const float4*)(zp + (size_t)s1 * F + c0);
      float4 z2 = *(const float4*)(zp + (size_t)s2 * F + c0);
      float4 z3 = *(const float4*)(zp + (size_t)s3 * F + c0);
      accE.x += a0*z0.x + a1*z1.x + a2*z2.x + a3*z3.x;
      accE.y += a0*z0.y + a1*z1.y + a2*z2.y + a3*z3.y;
      accE.z += a0*z0.z + a1*z1.z + a2*z2.z + a3*z3.z;
      accE.w += a0*z0.w + a1*z1.w + a2*z2.w + a3*z3.w;
    }
    for (; j < j1; j++) {
      int s = cs[j];
      float a = ap[j];
      float4 zv = *(const float4*)(zp + (size_t)s * F + c0);
      accE.x += a*zv.x; accE.y += a*zv.y; accE.z += a*zv.z; accE.w += a*zv.w;
    }
    float c = e ? coef1 : coef0;
    acc.x += c*accE.x; acc.y += c*accE.y; acc.z += c*accE.z; acc.w += c*accE.w;
  }
  if (MODE == 0) {
    acc.x += 0.5f*(bias[c0+0] + bias[F+c0+0]);
    acc.y += 0.5f*(bias[c0+1] + bias[F+c0+1]);
    acc.z += 0.5f*(bias[c0+2] + bias[F+c0+2]);
    acc.w += 0.5f*(bias[c0+3] + bias[F+c0+3]);
  } else {
    acc.x += coef0*bias[c0+0] + coef1*bias[F+c0+0];
    acc.y += coef0*bias[c0+1] + coef1*bias[F+c0+1];
    acc.z += coef0*bias[c0+2] + coef1*bias[F+c0+2];
    acc.w += coef0*bias[c0+3] + coef1*bias[F+c0+3];
  }
  *(float4*)(out + (size_t)d * F + c0) = acc;
}

// u[e][h][d][0..63] = sum_j alpha4[e][j][h] * h2[cs[j]];  16 lanes per dst.
__global__ __launch_bounds__(256) void agg_mh_k(
    const int* __restrict__ rp0, const int* __restrict__ cs0,
    const int* __restrict__ rp1, const int* __restrict__ cs1,
    const float* __restrict__ alpha, const float* __restrict__ h2,
    float* __restrict__ u) {
  int d = blockIdx.x * 16 + (threadIdx.x >> 4);
  int lane = threadIdx.x & 15, c0 = lane * 4;
  #pragma unroll
  for (int e = 0; e < 2; e++) {
    const int* rp = e ? rp1 : rp0;
    const int* cs = e ? cs1 : cs0;
    const float* ap = alpha + (size_t)e * EE * 4;
    float4 a0 = make_float4(0,0,0,0), a1 = make_float4(0,0,0,0);
    float4 a2 = make_float4(0,0,0,0), a3 = make_float4(0,0,0,0);
    int j0 = rp[d], j1 = rp[d + 1];
    int j = j0;
    for (; j + 4 <= j1; j += 4) {
      int sA = cs[j], sB = cs[j+1], sC = cs[j+2], sD = cs[j+3];
      float4 wA = *(const float4*)(ap + (size_t)j * 4);
      float4 wB = *(const float4*)(ap + (size_t)(j+1) * 4);
      float4 wC = *(const float4*)(ap + (size_t)(j+2) * 4);
      float4 wD = *(const float4*)(ap + (size_t)(j+3) * 4);
      float4 zA = *(const float4*)(h2 + (size_t)sA * 64 + c0);
      float4 zB = *(const float4*)(h2 + (size_t)sB * 64 + c0);
      float4 zC = *(const float4*)(h2 + (size_t)sC * 64 + c0);
      float4 zD = *(const float4*)(h2 + (size_t)sD * 64 + c0);
      a0.x += wA.x*zA.x + wB.x*zB.x + wC.x*zC.x + wD.x*zD.x;
      a0.y += wA.x*zA.y + wB.x*zB.y + wC.x*zC.y + wD.x*zD.y;
      a0.z += wA.x*zA.z + wB.x*zB.z + wC.x*zC.z + wD.x*zD.z;
      a0.w += wA.x*zA.w + wB.x*zB.w + wC.x*zC.w + wD.x*zD.w;
      a1.x += wA.y*zA.x + wB.y*zB.x + wC.y*zC.x + wD.y*zD.x;
      a1.y += wA.y*zA.y + wB.y*zB.y + wC.y*zC.y + wD.y*zD.y;
      a1.z += wA.y*zA.z + wB.y*zB.z + wC.y*zC.z + wD.y*zD.z;
      a1.w += wA.y*zA.w + wB.y*zB.w + wC.y*zC.w + wD.y*zD.w;
      a2.x += wA.z*zA.x + wB.z*zB.x + wC.z*zC.x + wD.z*zD.x;
      a2.y += wA.z*zA.y + wB.z*zB.y + wC.z*zC.y + wD.z*zD.y;
      a2.z += wA.z*zA.z + wB.z*zB.z + wC.z*zC.z + wD.z*zD.z;
      a2.w += wA.z*zA.w + wB.z*zB.w + wC.z*zC.w + wD.z*zD.w;
      a3.x += wA.w*zA.x + wB.w*zB.x + wC.w*zC.x + wD.w*zD.x;
      a3.y += wA.w*zA.y + wB.w*zB.y + wC.w*zC.y + wD.w*zD.y;
      a3.z += wA.w*zA.z + wB.w*zB.z + wC.w*zC.z + wD.w*zD.z;
      a3.w += wA.w*zA.w + wB.w*zB.w + wC.w*zC.w + wD.w*zD.w;
    }
    for (; j < j1; j++) {
      int s = cs[j];
      float4 w = *(const float4*)(ap + (size_t)j * 4);
      float4 z = *(const float4*)(h2 + (size_t)s * 64 + c0);
      a0.x += w.x*z.x; a0.y += w.x*z.y; a0.z += w.x*z.z; a0.w += w.x*z.w;
      a1.x += w.y*z.x; a1.y += w.y*z.y; a1.z += w.y*z.z; a1.w += w.y*z.w;
      a2.x += w.z*z.x; a2.y += w.z*z.y; a2.z += w.z*z.z; a2.w += w.z*z.w;
      a3.x += w.w*z.x; a3.y += w.w*z.y; a3.z += w.w*z.z; a3.w += w.w*z.w;
    }
    size_t base = ((size_t)e * 4 * NN + d) * 64 + c0;
    *(float4*)(u + base)                       = a0;
    *(float4*)(u + base + (size_t)NN * 64)     = a1;
    *(float4*)(u + base + (size_t)2 * NN * 64) = a2;
    *(float4*)(u + base + (size_t)3 * NN * 64) = a3;
  }
}

// out[d][h*64+f] = 0.5 * sum_e u[e][h][d][:] @ Wm[e][:, h*64+f]; 128-row tiles
__global__ __launch_bounds__(256) void out_gemm_k(
    const float* __restrict__ u, const float* __restrict__ Wm,
    float* __restrict__ out) {
  __shared__ float As[16][132];
  __shared__ float Bs[16][68];
  const int h = blockIdx.y;
  const int tid = threadIdx.x;
  const int tx = tid & 15, ty = tid >> 4;
  const int row0 = blockIdx.x * 128;
  float acc[2][16] = {};
  for (int e = 0; e < 2; e++) {
    const float* Up = u + (size_t)(e * 4 + h) * NN * 64;
    const float* Wp = Wm + (size_t)e * 64 * 256 + h * 64;
    for (int k0 = 0; k0 < 64; k0 += 16) {
      #pragma unroll
      for (int i = 0; i < 2; i++) {
        int t = tid + i * 256;
        int r = t >> 2, cv = t & 3;
        int rr = row0 + r; if (rr >= NN) rr = NN - 1;
        float4 v = *(const float4*)(Up + (size_t)rr * 64 + k0 + cv * 4);
        As[cv*4+0][r] = v.x; As[cv*4+1][r] = v.y;
        As[cv*4+2][r] = v.z; As[cv*4+3][r] = v.w;
      }
      {
        int r = tid >> 4, c = tid & 15;
        *(float4*)&Bs[r][c*4] = *(const float4*)(Wp + (size_t)(k0 + r) * 256 + c * 4);
      }
      __syncthreads();
      #pragma unroll
      for (int kk = 0; kk < 16; kk++) {
        float4 a0 = *(const float4*)&As[kk][ty*4];
        float4 a1 = *(const float4*)&As[kk][64 + ty*4];
        float4 bv = *(const float4*)&Bs[kk][tx*4];
        float* ac = acc[0];
        ac[0]  += a0.x*bv.x; ac[1]  += a0.x*bv.y; ac[2]  += a0.x*bv.z; ac[3]  += a0.x*bv.w;
        ac[4]  += a0.y*bv.x; ac[5]  += a0.y*bv.y; ac[6]  += a0.y*bv.z; ac[7]  += a0.y*bv.w;
        ac[8]  += a0.z*bv.x; ac[9]  += a0.z*bv.y; ac[10] += a0.z*bv.z; ac[11] += a0.z*bv.w;
        ac[12] += a0.w*bv.x; ac[13] += a0.w*bv.y; ac[14] += a0.w*bv.z; ac[15] += a0.w*bv.w;
        ac = acc[1];
        ac[0]  += a1.x*bv.x; ac[1]  += a1.x*bv.y; ac[2]  += a1.x*bv.z; ac[3]  += a1.x*bv.w;
        ac[4]  += a1.y*bv.x; ac[5]  += a1.y*bv.y; ac[6]  += a1.y*bv.z; ac[7]  += a1.y*bv.w;
        ac[8]  += a1.z*bv.x; ac[9]  += a1.z*bv.y; ac[10] += a1.z*bv.z; ac[11] += a1.z*bv.w;
        ac[12] += a1.w*bv.x; ac[13] += a1.w*bv.y; ac[14] += a1.w*bv.z; ac[15] += a1.w*bv.w;
      }
      __syncthreads();
    }
  }
  #pragma unroll
  for (int rp = 0; rp < 2; rp++) {
    #pragma unroll
    for (int i = 0; i < 4; i++) {
      int r = row0 + rp*64 + ty*4 + i;
      if (r < NN) {
        float* ac = acc[rp];
        *(float4*)(out + (size_t)r * 256 + h * 64 + tx * 4) =
            make_float4(0.5f*ac[i*4+0], 0.5f*ac[i*4+1], 0.5f*ac[i*4+2], 0.5f*ac[i*4+3]);
      }
    }
  }
}

// ================= epilogue: per-column mean-centering =================
__global__ __launch_bounds__(256) void colsum_k(
    const float* __restrict__ acc, float* __restrict__ sums) {
  int c = threadIdx.x;
  int nper = (NN + gridDim.x - 1) / gridDim.x;
  int n0 = blockIdx.x * nper;
  int n1 = n0 + nper; if (n1 > NN) n1 = NN;
  float s = 0.f;
  for (int n = n0; n < n1; n++) s += acc[(size_t)n * 256 + c];
  unsafeAtomicAdd(&sums[c], s);
}

__global__ __launch_bounds__(256) void center_k(
    float* __restrict__ out, const float* __restrict__ sums) {
  int i = blockIdx.x * 256 + threadIdx.x;
  if (i >= NN * 256) return;
  int c = i & 255;
  out[i] = out[i] - sums[c] * (1.0f / NN);
}

// ================= host-side launch =================
extern "C" void kernel_launch(void* const* d_in, const int* in_sizes, int n_in,
                              void* d_out, int out_size, void* d_ws, size_t ws_size,
                              hipStream_t stream) {
  const float* x   = (const float*)d_in[0];
  const int* src[2] = {(const int*)d_in[1], (const int*)d_in[3]};
  const int* dst[2] = {(const int*)d_in[2], (const int*)d_in[4]};
  const float* W1  = (const float*)d_in[5];
  const float* al1 = (const float*)d_in[6];
  const float* ar1 = (const float*)d_in[7];
  const float* b1  = (const float*)d_in[8];
  const float* W2  = (const float*)d_in[9];
  const float* al2 = (const float*)d_in[10];
  const float* ar2 = (const float*)d_in[11];
  const float* b2  = (const float*)d_in[12];
  const float* Wm  = (const float*)d_in[13];
  const float* alm = (const float*)d_in[14];
  const float* arm = (const float*)d_in[15];
  // d_in[16] = bm: cancels under per-head mean-centering
  const float* fcw = (const float*)d_in[17];
  float* out = (float*)d_out;

  float* ws = (float*)d_ws;
  // zu region [0, 25.6M): z for L1 (12.8M) / L2 (6.4M), then u (25.6M) for MH
  float* zu     = ws;
  float* alpha1 = ws + 24000000;   // 1.6M floats, inside zu tail (free in L1/L2 phases)
  float* h1     = ws + 25600000;   // 6.4M; reused as alpha4 (2*EE*4 = 6.4M) in MH phase
  float* alpha4 = h1;
  float* h2     = ws + 32000000;   // 3.2M
  float* el     = ws + 35200000;   // 0.4M
  float* er     = ws + 35600000;   // 0.4M
  float* csum   = ws + 36000000;   // 256
  float* wl1    = ws + 36000256;   // 256
  float* wr1    = wl1 + 256;
  float* wl2    = wr1 + 256;
  float* wr2    = wl2 + 256;
  float* wlm    = wr2 + 256;       // 512
  float* wrm    = wlm + 512;       // 512
  int* rowptr[2], *csr_src[2];
  rowptr[0]  = (int*)(wrm + 512);
  rowptr[1]  = rowptr[0] + 50001;
  csr_src[0] = rowptr[1] + 50001;
  csr_src[1] = csr_src[0] + EE;
  // CSR build scratch aliases el/er/alpha1
  int* deg[2]    = {(int*)el, (int*)el + 50000};
  int* inc[2]    = {(int*)er, (int*)er + 50000};
  int* cursor[2] = {(int*)alpha1, (int*)alpha1 + 50000};
  int* bsum[2]   = {(int*)alpha1 + 100000, (int*)alpha1 + 100128};

  // ---- CSR build ----
  hipMemsetAsync(deg[0], 0, 2 * 50000 * sizeof(int), stream);
  hipMemsetAsync(cursor[0], 0, 2 * 50000 * sizeof(int), stream);
  hipMemsetAsync(csum, 0, 256 * sizeof(float), stream);
  for (int e = 0; e < 2; e++) {
    deg_k<<<3125, 256, 0, stream>>>(dst[e], deg[e]);
    scan1_k<<<98, 512, 0, stream>>>(deg[e], inc[e], bsum[e]);
    scan2_k<<<1, 128, 0, stream>>>(bsum[e], 98);
    scan3_k<<<196, 256, 0, stream>>>(deg[e], inc[e], bsum[e], rowptr[e]);
    csr_scatter_k<<<3125, 256, 0, stream>>>(src[e], dst[e], rowptr[e], cursor[e], csr_src[e]);
  }

  // ---- fold attention vectors through weights ----
  fold_k<<<8, 256, 0, stream>>>(W1, al1, ar1, W2, al2, ar2, Wm, alm, arm,
                                wl1, wr1, wl2, wr2, wlm, wrm);

  // ================= layer 1: IN=128 -> HID=128 =================
  dot2_k<<<3125, 256, 0, stream>>>(x, wl1, wr1, el, er);
  gemm_t<128><<<dim3(391, 1, 2), 256, 0, stream>>>(x, W1, zu, NN, 128);
  alpha1_k<<<391, 256, 0, stream>>>(
      rowptr[0], csr_src[0], rowptr[1], csr_src[1], el, er, alpha1);
  agg1_k<128,0><<<NN/8, 256, 0, stream>>>(
      rowptr[0], csr_src[0], rowptr[1], csr_src[1], alpha1, zu, b1, fcw, h1);

  // ================= layer 2: HID=128 -> OUT=64, fc agg =================
  dot2_k<<<3125, 256, 0, stream>>>(h1, wl2, wr2, el, er);
  gemm_t<64><<<dim3(391, 1, 2), 256, 0, stream>>>(h1, W2, zu, NN, 128);
  alpha1_k<<<391, 256, 0, stream>>>(
      rowptr[0], csr_src[0], rowptr[1], csr_src[1], el, er, alpha1);
  agg1_k<64,1><<<NN/16, 256, 0, stream>>>(
      rowptr[0], csr_src[0], rowptr[1], csr_src[1], alpha1, zu, b2, fcw, h2);

  // ================= MH layer: gather h2, post-GEMM with Wm =================
  dotm_k<<<6250, 256, 0, stream>>>(h2, wlm, wrm, el, er);
  alpha4_k<<<391, 256, 0, stream>>>(
      rowptr[0], csr_src[0], rowptr[1], csr_src[1], el, er, alpha4);
  agg_mh_k<<<3125, 256, 0, stream>>>(
      rowptr[0], csr_src[0], rowptr[1], csr_src[1], alpha4, h2, zu);
  out_gemm_k<<<dim3(391, 4), 256, 0, stream>>>(zu, Wm, out);

  colsum_k<<<256, 256, 0, stream>>>(out, csum);
  center_k<<<50000, 256, 0, stream>>>(out, csum);
}

// Round 6
// 844.653 us; speedup vs baseline: 12.6266x; 1.0053x over previous
//
#include <hip/hip_runtime.h>

#define NN 50000
#define EE 800000
#define NETYPE 2

// ================= CSR build (both etypes per launch) =================
__global__ __launch_bounds__(256) void deg2_k(
    const int* __restrict__ dst0, const int* __restrict__ dst1,
    int* __restrict__ deg) {
  int i = blockIdx.x * 256 + threadIdx.x;
  if (i < EE) atomicAdd(&deg[dst0[i]], 1);
  else if (i < 2 * EE) atomicAdd(&deg[50000 + dst1[i - EE]], 1);
}

__global__ __launch_bounds__(512) void scan1_k(const int* __restrict__ deg,
                                               int* __restrict__ inc,
                                               int* __restrict__ bsum) {
  __shared__ int s[512];
  int e = blockIdx.y;
  int t = threadIdx.x, i = blockIdx.x * 512 + t;
  int v = (i < NN) ? deg[e * 50000 + i] : 0;
  s[t] = v; __syncthreads();
  #pragma unroll
  for (int off = 1; off < 512; off <<= 1) {
    int u = (t >= off) ? s[t - off] : 0;
    __syncthreads();
    s[t] += u;
    __syncthreads();
  }
  if (i < NN) inc[e * 50000 + i] = s[t];
  if (t == 511) bsum[e * 128 + blockIdx.x] = s[511];
}

__global__ __launch_bounds__(128) void scan2_k(int* __restrict__ bsum, int nb) {
  __shared__ int s[128];
  int e = blockIdx.x;
  int t = threadIdx.x;
  int v = (t < nb) ? bsum[e * 128 + t] : 0;
  s[t] = v; __syncthreads();
  #pragma unroll
  for (int off = 1; off < 128; off <<= 1) {
    int u = (t >= off) ? s[t - off] : 0;
    __syncthreads();
    s[t] += u;
    __syncthreads();
  }
  if (t < nb) bsum[e * 128 + t] = s[t] - v;
}

__global__ __launch_bounds__(256) void scan3_k(const int* __restrict__ deg,
                                               const int* __restrict__ inc,
                                               const int* __restrict__ bsum,
                                               int* __restrict__ rowptr) {
  int e = blockIdx.y;
  int i = blockIdx.x * 256 + threadIdx.x;
  if (i < NN)
    rowptr[e * 50001 + i] =
        inc[e * 50000 + i] - deg[e * 50000 + i] + bsum[e * 128 + (i >> 9)];
  if (i == NN) rowptr[e * 50001 + NN] = EE;
}

__global__ __launch_bounds__(256) void csr_scatter2_k(
    const int* __restrict__ src0, const int* __restrict__ dst0,
    const int* __restrict__ src1, const int* __restrict__ dst1,
    const int* __restrict__ rowptr, int* __restrict__ cursor,
    int* __restrict__ csr_src) {
  int i = blockIdx.x * 256 + threadIdx.x;
  if (i >= 2 * EE) return;
  int e = i >= EE;
  int k = i - e * EE;
  int d = e ? dst1[k] : dst0[k];
  int s = e ? src1[k] : src0[k];
  int pos = atomicAdd(&cursor[e * 50000 + d], 1);
  csr_src[(size_t)e * EE + rowptr[e * 50001 + d] + pos] = s;
}

// ======== fold a_l/a_r through weights: wl[e] = W[e] @ a[e] ========
__global__ __launch_bounds__(256) void fold_k(
    const float* __restrict__ W1, const float* __restrict__ al1, const float* __restrict__ ar1,
    const float* __restrict__ W2, const float* __restrict__ al2, const float* __restrict__ ar2,
    const float* __restrict__ Wm, const float* __restrict__ alm, const float* __restrict__ arm,
    float* __restrict__ wl1, float* __restrict__ wr1,
    float* __restrict__ wl2, float* __restrict__ wr2,
    float* __restrict__ wlm, float* __restrict__ wrm) {
  int t = blockIdx.x * 256 + threadIdx.x;  // 2048 total
  if (t < 512) {
    int lr = t >> 8, e = (t >> 7) & 1, k = t & 127;
    const float* a = (lr ? ar1 : al1) + e * 128;
    const float* w = W1 + ((size_t)e * 128 + k) * 128;
    float s = 0.f;
    for (int f = 0; f < 128; f++) s += w[f] * a[f];
    (lr ? wr1 : wl1)[e * 128 + k] = s;
  } else if (t < 1024) {
    int u = t - 512;
    int lr = u >> 8, e = (u >> 7) & 1, k = u & 127;
    const float* a = (lr ? ar2 : al2) + e * 64;
    const float* w = W2 + ((size_t)e * 128 + k) * 64;
    float s = 0.f;
    for (int f = 0; f < 64; f++) s += w[f] * a[f];
    (lr ? wr2 : wl2)[e * 128 + k] = s;
  } else {
    int u = t - 1024;
    int lr = u >> 9, e = (u >> 8) & 1, h = (u >> 6) & 3, k = u & 63;
    const float* a = (lr ? arm : alm) + (e * 4 + h) * 64;
    const float* w = Wm + ((size_t)e * 64 + k) * 256 + h * 64;
    float s = 0.f;
    for (int f = 0; f < 64; f++) s += w[f] * a[f];
    (lr ? wrm : wlm)[(e * 4 + h) * 64 + k] = s;
  }
}

// ================= el/er dots from node features, K=128, both etypes ==========
__global__ __launch_bounds__(256) void dot2_k(
    const float* __restrict__ X, const float* __restrict__ wl,
    const float* __restrict__ wr, float* __restrict__ el, float* __restrict__ er) {
  int n = blockIdx.x * 16 + (threadIdx.x >> 4);
  int lane = threadIdx.x & 15;
  if (n >= NN) return;
  float p[4] = {0.f, 0.f, 0.f, 0.f};
  #pragma unroll
  for (int i = 0; i < 2; i++) {
    int c = (lane + i * 16) * 4;
    float4 xv = *(const float4*)(X + (size_t)n * 128 + c);
    #pragma unroll
    for (int e = 0; e < 2; e++) {
      float4 a = *(const float4*)(wl + e * 128 + c);
      float4 b = *(const float4*)(wr + e * 128 + c);
      p[e*2+0] += xv.x*a.x + xv.y*a.y + xv.z*a.z + xv.w*a.w;
      p[e*2+1] += xv.x*b.x + xv.y*b.y + xv.z*b.z + xv.w*b.w;
    }
  }
  #pragma unroll
  for (int off = 1; off < 16; off <<= 1) {
    #pragma unroll
    for (int i = 0; i < 4; i++) p[i] += __shfl_xor(p[i], off);
  }
  if (lane == 0) {
    el[n] = p[0]; er[n] = p[1];
    el[NN + n] = p[2]; er[NN + n] = p[3];
  }
}

// MH: elm[e][n][h] = h2[n] . wlm[e][h]
__global__ __launch_bounds__(256) void dotm_k(
    const float* __restrict__ h2, const float* __restrict__ wl,
    const float* __restrict__ wr, float* __restrict__ el, float* __restrict__ er) {
  int g = blockIdx.x * 16 + (threadIdx.x >> 4);
  int lane = threadIdx.x & 15;
  if (g >= 2 * NN) return;
  int e = g / NN, n = g % NN;
  float4 z4 = *(const float4*)(h2 + (size_t)n * 64 + lane * 4);
  float p[8];
  #pragma unroll
  for (int h = 0; h < 4; h++) {
    float4 a = *(const float4*)(wl + (e * 4 + h) * 64 + lane * 4);
    float4 b = *(const float4*)(wr + (e * 4 + h) * 64 + lane * 4);
    p[h]     = z4.x*a.x + z4.y*a.y + z4.z*a.z + z4.w*a.w;
    p[4 + h] = z4.x*b.x + z4.y*b.y + z4.z*b.z + z4.w*b.w;
  }
  #pragma unroll
  for (int off = 1; off < 16; off <<= 1) {
    #pragma unroll
    for (int i = 0; i < 8; i++) p[i] += __shfl_xor(p[i], off);
  }
  if (lane == 0) *(float4*)(el + (size_t)g * 4) = make_float4(p[0], p[1], p[2], p[3]);
  if (lane == 8) *(float4*)(er + (size_t)g * 4) = make_float4(p[4], p[5], p[6], p[7]);
}

// ===== per-(e,d): denominator (no max-sub; |v|<~10 fp32-safe) + write alpha ====
__global__ __launch_bounds__(256) void alpha1_k(
    const int* __restrict__ rowptr, const int* __restrict__ csr_src,
    const float* __restrict__ el, const float* __restrict__ er,
    float* __restrict__ alpha) {
  int t = blockIdx.x * 256 + threadIdx.x;
  if (t >= 2 * NN) return;
  int e = t / NN, d = t % NN;
  const int* rp = rowptr + e * 50001;
  const int* cs = csr_src + (size_t)e * EE;
  const float* elp = el + (size_t)e * NN;
  float erd = er[t];
  int j0 = rp[d], j1 = rp[d + 1];
  float sm = 0.f;
  int j = j0;
  for (; j + 4 <= j1; j += 4) {
    float v0 = elp[cs[j]]   + erd; v0 = v0 >= 0.f ? v0 : 0.2f*v0;
    float v1 = elp[cs[j+1]] + erd; v1 = v1 >= 0.f ? v1 : 0.2f*v1;
    float v2 = elp[cs[j+2]] + erd; v2 = v2 >= 0.f ? v2 : 0.2f*v2;
    float v3 = elp[cs[j+3]] + erd; v3 = v3 >= 0.f ? v3 : 0.2f*v3;
    sm += __expf(v0) + __expf(v1) + __expf(v2) + __expf(v3);
  }
  for (; j < j1; j++) {
    float v = elp[cs[j]] + erd; v = v >= 0.f ? v : 0.2f*v;
    sm += __expf(v);
  }
  float inv = 1.f / fmaxf(sm, 1e-9f);
  float* ap = alpha + (size_t)e * EE;
  for (j = j0; j < j1; j++) {
    float v = elp[cs[j]] + erd; v = v >= 0.f ? v : 0.2f*v;
    ap[j] = __expf(v) * inv;
  }
}

// MH variant: 4 heads, float4 alpha per edge
__global__ __launch_bounds__(256) void alpha4_k(
    const int* __restrict__ rowptr, const int* __restrict__ csr_src,
    const float* __restrict__ el, const float* __restrict__ er,
    float* __restrict__ alpha) {
  int t = blockIdx.x * 256 + threadIdx.x;
  if (t >= 2 * NN) return;
  int e = t / NN, d = t % NN;
  const int* rp = rowptr + e * 50001;
  const int* cs = csr_src + (size_t)e * EE;
  const float* elp = el + (size_t)e * NN * 4;
  float4 er4 = *(const float4*)(er + (size_t)t * 4);
  int j0 = rp[d], j1 = rp[d + 1];
  float4 sm = make_float4(0.f, 0.f, 0.f, 0.f);
  for (int j = j0; j < j1; j++) {
    float4 v = *(const float4*)(elp + (size_t)cs[j] * 4);
    v.x += er4.x; v.y += er4.y; v.z += er4.z; v.w += er4.w;
    v.x = v.x >= 0.f ? v.x : 0.2f*v.x; v.y = v.y >= 0.f ? v.y : 0.2f*v.y;
    v.z = v.z >= 0.f ? v.z : 0.2f*v.z; v.w = v.w >= 0.f ? v.w : 0.2f*v.w;
    sm.x += __expf(v.x); sm.y += __expf(v.y);
    sm.z += __expf(v.z); sm.w += __expf(v.w);
  }
  float4 inv = make_float4(1.f / fmaxf(sm.x, 1e-9f), 1.f / fmaxf(sm.y, 1e-9f),
                           1.f / fmaxf(sm.z, 1e-9f), 1.f / fmaxf(sm.w, 1e-9f));
  float* ap = alpha + (size_t)e * EE * 4;
  for (int j = j0; j < j1; j++) {
    float4 v = *(const float4*)(elp + (size_t)cs[j] * 4);
    v.x += er4.x; v.y += er4.y; v.z += er4.z; v.w += er4.w;
    v.x = v.x >= 0.f ? v.x : 0.2f*v.x; v.y = v.y >= 0.f ? v.y : 0.2f*v.y;
    v.z = v.z >= 0.f ? v.z : 0.2f*v.z; v.w = v.w >= 0.f ? v.w : 0.2f*v.w;
    *(float4*)(ap + (size_t)j * 4) =
        make_float4(__expf(v.x) * inv.x, __expf(v.y) * inv.y,
                    __expf(v.z) * inv.z, __expf(v.w) * inv.w);
  }
}

// ===== layer1 gather: u1[e][d][0..127] = sum_j alpha[e][j] * x[cs[j]] =====
__global__ __launch_bounds__(256) void agg_x_k(
    const int* __restrict__ rowptr, const int* __restrict__ csr_src,
    const float* __restrict__ alpha, const float* __restrict__ x,
    float* __restrict__ u1) {
  int d = blockIdx.x * 8 + (threadIdx.x >> 5);
  int lane = threadIdx.x & 31;
  int c0 = lane * 4;
  #pragma unroll
  for (int e = 0; e < 2; e++) {
    const int* rp = rowptr + e * 50001;
    const int* cs = csr_src + (size_t)e * EE;
    const float* ap = alpha + (size_t)e * EE;
    int j0 = rp[d], j1 = rp[d + 1];
    float4 acc = make_float4(0.f, 0.f, 0.f, 0.f);
    int j = j0;
    for (; j + 4 <= j1; j += 4) {
      int s0 = cs[j], s1 = cs[j+1], s2 = cs[j+2], s3 = cs[j+3];
      float a0 = ap[j], a1 = ap[j+1], a2 = ap[j+2], a3 = ap[j+3];
      float4 z0 = *(const float4*)(x + (size_t)s0 * 128 + c0);
      float4 z1 = *(const float4*)(x + (size_t)s1 * 128 + c0);
      float4 z2 = *(const float4*)(x + (size_t)s2 * 128 + c0);
      float4 z3 = *(const float4*)(x + (size_t)s3 * 128 + c0);
      acc.x += a0*z0.x + a1*z1.x + a2*z2.x + a3*z3.x;
      acc.y += a0*z0.y + a1*z1.y + a2*z2.y + a3*z3.y;
      acc.z += a0*z0.z + a1*z1.z + a2*z2.z + a3*z3.z;
      acc.w += a0*z0.w + a1*z1.w + a2*z2.w + a3*z3.w;
    }
    for (; j < j1; j++) {
      int s = cs[j];
      float a = ap[j];
      float4 zv = *(const float4*)(x + (size_t)s * 128 + c0);
      acc.x += a*zv.x; acc.y += a*zv.y; acc.z += a*zv.z; acc.w += a*zv.w;
    }
    *(float4*)(u1 + ((size_t)e * NN + d) * 128 + c0) = acc;
  }
}

// ===== h1 = 0.5*(u1[0]@W1[0] + u1[1]@W1[1]) + 0.5*(b1[0]+b1[1]) =====
__global__ __launch_bounds__(256) void ugemm1_k(
    const float* __restrict__ u1, const float* __restrict__ W1,
    const float* __restrict__ b1, float* __restrict__ h1) {
  __shared__ float As[16][132];
  __shared__ float Bs[16][132];
  const int tid = threadIdx.x;
  const int tx = tid & 15, ty = tid >> 4;
  const int row0 = blockIdx.x * 128;
  float acc[2][2][16] = {};
  for (int e = 0; e < 2; e++) {
    const float* Up = u1 + (size_t)e * NN * 128;
    const float* Wp = W1 + (size_t)e * 128 * 128;
    for (int k0 = 0; k0 < 128; k0 += 16) {
      #pragma unroll
      for (int i = 0; i < 2; i++) {
        int t = tid + i * 256;
        int r = t >> 2, cv = t & 3;
        int rr = row0 + r; if (rr >= NN) rr = NN - 1;
        float4 v = *(const float4*)(Up + (size_t)rr * 128 + k0 + cv * 4);
        As[cv*4+0][r] = v.x; As[cv*4+1][r] = v.y;
        As[cv*4+2][r] = v.z; As[cv*4+3][r] = v.w;
      }
      #pragma unroll
      for (int i = 0; i < 2; i++) {
        int t = tid + i * 256;
        int r = t >> 5, c = t & 31;
        *(float4*)&Bs[r][c*4] = *(const float4*)(Wp + (size_t)(k0 + r) * 128 + c * 4);
      }
      __syncthreads();
      #pragma unroll
      for (int kk = 0; kk < 16; kk++) {
        float4 a[2], b[2];
        a[0] = *(const float4*)&As[kk][ty*4];
        a[1] = *(const float4*)&As[kk][64 + ty*4];
        b[0] = *(const float4*)&Bs[kk][tx*4];
        b[1] = *(const float4*)&Bs[kk][64 + tx*4];
        #pragma unroll
        for (int rp = 0; rp < 2; rp++) {
          #pragma unroll
          for (int cp = 0; cp < 2; cp++) {
            float* ac = acc[rp][cp];
            float4 av = a[rp], bv = b[cp];
            ac[0]  += av.x*bv.x; ac[1]  += av.x*bv.y; ac[2]  += av.x*bv.z; ac[3]  += av.x*bv.w;
            ac[4]  += av.y*bv.x; ac[5]  += av.y*bv.y; ac[6]  += av.y*bv.z; ac[7]  += av.y*bv.w;
            ac[8]  += av.z*bv.x; ac[9]  += av.z*bv.y; ac[10] += av.z*bv.z; ac[11] += av.z*bv.w;
            ac[12] += av.w*bv.x; ac[13] += av.w*bv.y; ac[14] += av.w*bv.z; ac[15] += av.w*bv.w;
          }
        }
      }
      __syncthreads();
    }
  }
  #pragma unroll
  for (int rp = 0; rp < 2; rp++) {
    #pragma unroll
    for (int cp = 0; cp < 2; cp++) {
      int c = cp * 64 + tx * 4;
      float4 bb = make_float4(0.5f*(b1[c] + b1[128+c]),   0.5f*(b1[c+1] + b1[128+c+1]),
                              0.5f*(b1[c+2] + b1[128+c+2]), 0.5f*(b1[c+3] + b1[128+c+3]));
      #pragma unroll
      for (int i = 0; i < 4; i++) {
        int r = row0 + rp*64 + ty*4 + i;
        if (r < NN) {
          float* ac = acc[rp][cp];
          *(float4*)(h1 + (size_t)r * 128 + c) =
              make_float4(0.5f*ac[i*4+0] + bb.x, 0.5f*ac[i*4+1] + bb.y,
                          0.5f*ac[i*4+2] + bb.z, 0.5f*ac[i*4+3] + bb.w);
        }
      }
    }
  }
}

// ================= GEMM: Z[e] = X @ W[e], 128x64 tiles fp32 (layer 2) =========
__global__ __launch_bounds__(256) void gemm64_k(
    const float* __restrict__ X, const float* __restrict__ W,
    float* __restrict__ Z, int M, int K) {
  __shared__ float As[16][132];
  __shared__ float Bs[16][68];
  const int e = blockIdx.z;
  const float* Wp = W + (size_t)e * K * 64;
  float* Zp = Z + (size_t)e * M * 64;
  const int tid = threadIdx.x;
  const int tx = tid & 15, ty = tid >> 4;
  const int row0 = blockIdx.x * 128;
  float acc[2][16] = {};
  for (int k0 = 0; k0 < K; k0 += 16) {
    #pragma unroll
    for (int i = 0; i < 2; i++) {
      int t = tid + i * 256;
      int r = t >> 2, cv = t & 3;
      int rr = row0 + r; if (rr >= M) rr = M - 1;
      float4 v = *(const float4*)(X + (size_t)rr * K + k0 + cv * 4);
      As[cv*4+0][r] = v.x; As[cv*4+1][r] = v.y;
      As[cv*4+2][r] = v.z; As[cv*4+3][r] = v.w;
    }
    {
      int r = tid >> 4, c = tid & 15;
      *(float4*)&Bs[r][c*4] = *(const float4*)(Wp + (size_t)(k0 + r) * 64 + c * 4);
    }
    __syncthreads();
    #pragma unroll
    for (int kk = 0; kk < 16; kk++) {
      float4 a0 = *(const float4*)&As[kk][ty*4];
      float4 a1 = *(const float4*)&As[kk][64 + ty*4];
      float4 bv = *(const float4*)&Bs[kk][tx*4];
      float* ac = acc[0];
      ac[0]  += a0.x*bv.x; ac[1]  += a0.x*bv.y; ac[2]  += a0.x*bv.z; ac[3]  += a0.x*bv.w;
      ac[4]  += a0.y*bv.x; ac[5]  += a0.y*bv.y; ac[6]  += a0.y*bv.z; ac[7]  += a0.y*bv.w;
      ac[8]  += a0.z*bv.x; ac[9]  += a0.z*bv.y; ac[10] += a0.z*bv.z; ac[11] += a0.z*bv.w;
      ac[12] += a0.w*bv.x; ac[13] += a0.w*bv.y; ac[14] += a0.w*bv.z; ac[15] += a0.w*bv.w;
      ac = acc[1];
      ac[0]  += a1.x*bv.x; ac[1]  += a1.x*bv.y; ac[2]  += a1.x*bv.z; ac[3]  += a1.x*bv.w;
      ac[4]  += a1.y*bv.x; ac[5]  += a1.y*bv.y; ac[6]  += a1.y*bv.z; ac[7]  += a1.y*bv.w;
      ac[8]  += a1.z*bv.x; ac[9]  += a1.z*bv.y; ac[10] += a1.z*bv.z; ac[11] += a1.z*bv.w;
      ac[12] += a1.w*bv.x; ac[13] += a1.w*bv.y; ac[14] += a1.w*bv.z; ac[15] += a1.w*bv.w;
    }
    __syncthreads();
  }
  #pragma unroll
  for (int rp = 0; rp < 2; rp++) {
    #pragma unroll
    for (int i = 0; i < 4; i++) {
      int r = row0 + rp*64 + ty*4 + i;
      if (r < M) {
        float* ac = acc[rp];
        *(float4*)(Zp + (size_t)r * 64 + tx*4) =
            make_float4(ac[i*4+0], ac[i*4+1], ac[i*4+2], ac[i*4+3]);
      }
    }
  }
}

// ========== layer-2 gather-aggregate with fc coefs + bias ==========
__global__ __launch_bounds__(256) void agg2_k(
    const int* __restrict__ rowptr, const int* __restrict__ csr_src,
    const float* __restrict__ alpha, const float* __restrict__ z,
    const float* __restrict__ bias, const float* __restrict__ fcw,
    float* __restrict__ out) {
  int d = blockIdx.x * 16 + (threadIdx.x >> 4);
  int lane = threadIdx.x & 15;
  int c0 = lane * 4;
  float coef0 = 0.5f * (fcw[0] + fcw[2]);
  float coef1 = 0.5f * (fcw[1] + fcw[3]);
  float4 acc = make_float4(0.f, 0.f, 0.f, 0.f);
  #pragma unroll
  for (int e = 0; e < 2; e++) {
    const int* rp = rowptr + e * 50001;
    const int* cs = csr_src + (size_t)e * EE;
    const float* ap = alpha + (size_t)e * EE;
    const float* zp = z + (size_t)e * NN * 64;
    int j0 = rp[d], j1 = rp[d + 1];
    float4 accE = make_float4(0.f, 0.f, 0.f, 0.f);
    int j = j0;
    for (; j + 4 <= j1; j += 4) {
      int s0 = cs[j], s1 = cs[j+1], s2 = cs[j+2], s3 = cs[j+3];
      float a0 = ap[j], a1 = ap[j+1], a2 = ap[j+2], a3 = ap[j+3];
      float4 z0 = *(const float4*)(zp + (size_t)s0 * 64 + c0);
      float4 z1 = *(const float4*)(zp + (size_t)s1 * 64 + c0);
      float4 z2 = *(const float4*)(zp + (size_t)s2 * 64 + c0);
      float4 z3 = *(const float4*)(zp + (size_t)s3 * 64 + c0);
      accE.x += a0*z0.x + a1*z1.x + a2*z2.x + a3*z3.x;
      accE.y += a0*z0.y + a1*z1.y + a2*z2.y + a3*z3.y;
      accE.z += a0*z0.z + a1*z1.z + a2*z2.z + a3*z3.z;
      accE.w += a0*z0.w + a1*z1.w + a2*z2.w + a3*z3.w;
    }
    for (; j < j1; j++) {
      int s = cs[j];
      float a = ap[j];
      float4 zv = *(const float4*)(zp + (size_t)s * 64 + c0);
      accE.x += a*zv.x; accE.y += a*zv.y; accE.z += a*zv.z; accE.w += a*zv.w;
    }
    float c = e ? coef1 : coef0;
    acc.x += c*accE.x; acc.y += c*accE.y; acc.z += c*accE.z; acc.w += c*accE.w;
  }
  acc.x += coef0*bias[c0+0] + coef1*bias[64+c0+0];
  acc.y += coef0*bias[c0+1] + coef1*bias[64+c0+1];
  acc.z += coef0*bias[c0+2] + coef1*bias[64+c0+2];
  acc.w += coef0*bias[c0+3] + coef1*bias[64+c0+3];
  *(float4*)(out + (size_t)d * 64 + c0) = acc;
}

// u[e][h][d][0..63] = sum_j alpha4[e][j][h] * h2[cs[j]];  16 lanes per dst.
__global__ __launch_bounds__(256) void agg_mh_k(
    const int* __restrict__ rowptr, const int* __restrict__ csr_src,
    const float* __restrict__ alpha, const float* __restrict__ h2,
    float* __restrict__ u) {
  int d = blockIdx.x * 16 + (threadIdx.x >> 4);
  int lane = threadIdx.x & 15, c0 = lane * 4;
  #pragma unroll
  for (int e = 0; e < 2; e++) {
    const int* rp = rowptr + e * 50001;
    const int* cs = csr_src + (size_t)e * EE;
    const float* ap = alpha + (size_t)e * EE * 4;
    float4 a0 = make_float4(0,0,0,0), a1 = make_float4(0,0,0,0);
    float4 a2 = make_float4(0,0,0,0), a3 = make_float4(0,0,0,0);
    int j0 = rp[d], j1 = rp[d + 1];
    int j = j0;
    for (; j + 4 <= j1; j += 4) {
      int sA = cs[j], sB = cs[j+1], sC = cs[j+2], sD = cs[j+3];
      float4 wA = *(const float4*)(ap + (size_t)j * 4);
      float4 wB = *(const float4*)(ap + (size_t)(j+1) * 4);
      float4 wC = *(const float4*)(ap + (size_t)(j+2) * 4);
      float4 wD = *(const float4*)(ap + (size_t)(j+3) * 4);
      float4 zA = *(const float4*)(h2 + (size_t)sA * 64 + c0);
      float4 zB = *(const float4*)(h2 + (size_t)sB * 64 + c0);
      float4 zC = *(const float4*)(h2 + (size_t)sC * 64 + c0);
      float4 zD = *(const float4*)(h2 + (size_t)sD * 64 + c0);
      a0.x += wA.x*zA.x + wB.x*zB.x + wC.x*zC.x + wD.x*zD.x;
      a0.y += wA.x*zA.y + wB.x*zB.y + wC.x*zC.y + wD.x*zD.y;
      a0.z += wA.x*zA.z + wB.x*zB.z + wC.x*zC.z + wD.x*zD.z;
      a0.w += wA.x*zA.w + wB.x*zB.w + wC.x*zC.w + wD.x*zD.w;
      a1.x += wA.y*zA.x + wB.y*zB.x + wC.y*zC.x + wD.y*zD.x;
      a1.y += wA.y*zA.y + wB.y*zB.y + wC.y*zC.y + wD.y*zD.y;
      a1.z += wA.y*zA.z + wB.y*zB.z + wC.y*zC.z + wD.y*zD.z;
      a1.w += wA.y*zA.w + wB.y*zB.w + wC.y*zC.w + wD.y*zD.w;
      a2.x += wA.z*zA.x + wB.z*zB.x + wC.z*zC.x + wD.z*zD.x;
      a2.y += wA.z*zA.y + wB.z*zB.y + wC.z*zC.y + wD.z*zD.y;
      a2.z += wA.z*zA.z + wB.z*zB.z + wC.z*zC.z + wD.z*zD.z;
      a2.w += wA.z*zA.w + wB.z*zB.w + wC.z*zC.w + wD.z*zD.w;
      a3.x += wA.w*zA.x + wB.w*zB.x + wC.w*zC.x + wD.w*zD.x;
      a3.y += wA.w*zA.y + wB.w*zB.y + wC.w*zC.y + wD.w*zD.y;
      a3.z += wA.w*zA.z + wB.w*zB.z + wC.w*zC.z + wD.w*zD.z;
      a3.w += wA.w*zA.w + wB.w*zB.w + wC.w*zC.w + wD.w*zD.w;
    }
    for (; j < j1; j++) {
      int s = cs[j];
      float4 w = *(const float4*)(ap + (size_t)j * 4);
      float4 z = *(const float4*)(h2 + (size_t)s * 64 + c0);
      a0.x += w.x*z.x; a0.y += w.x*z.y; a0.z += w.x*z.z; a0.w += w.x*z.w;
      a1.x += w.y*z.x; a1.y += w.y*z.y; a1.z += w.y*z.z; a1.w += w.y*z.w;
      a2.x += w.z*z.x; a2.y += w.z*z.y; a2.z += w.z*z.z; a2.w += w.z*z.w;
      a3.x += w.w*z.x; a3.y += w.w*z.y; a3.z += w.w*z.z; a3.w += w.w*z.w;
    }
    size_t base = ((size_t)e * 4 * NN + d) * 64 + c0;
    *(float4*)(u + base)                       = a0;
    *(float4*)(u + base + (size_t)NN * 64)     = a1;
    *(float4*)(u + base + (size_t)2 * NN * 64) = a2;
    *(float4*)(u + base + (size_t)3 * NN * 64) = a3;
  }
}

// ===== column sums of u per (e,h): usum[(e*4+h)*64 + c] = sum_n u[e][h][n][c] =====
__global__ __launch_bounds__(256) void colsum_u_k(
    const float* __restrict__ u, float* __restrict__ usum) {
  __shared__ float lds[4][64];
  int eh = blockIdx.x >> 6;          // 0..7
  int chunk = blockIdx.x & 63;
  int c = threadIdx.x & 63, rg = threadIdx.x >> 6;
  const float* up = u + (size_t)eh * NN * 64;
  int n0 = chunk * 782;
  int n1 = n0 + 782; if (n1 > NN) n1 = NN;
  float s = 0.f;
  for (int n = n0 + rg; n < n1; n += 4) s += up[(size_t)n * 64 + c];
  lds[rg][c] = s;
  __syncthreads();
  if (rg == 0) {
    float t = lds[0][c] + lds[1][c] + lds[2][c] + lds[3][c];
    unsafeAtomicAdd(&usum[eh * 64 + c], t);
  }
}

// ===== mean[c] = 0.5/NN * sum_e usum[e][h]·Wm[e][:,c]  (c = h*64+f) =====
__global__ __launch_bounds__(256) void mean_k(
    const float* __restrict__ usum, const float* __restrict__ Wm,
    float* __restrict__ mean) {
  int c = threadIdx.x;            // 0..255
  int h = c >> 6;
  float s = 0.f;
  for (int e = 0; e < 2; e++) {
    const float* us = usum + (e * 4 + h) * 64;
    const float* wp = Wm + (size_t)e * 64 * 256 + c;
    for (int k = 0; k < 64; k++) s += us[k] * wp[(size_t)k * 256];
  }
  mean[c] = s * (0.5f / NN);
}

// out[d][h*64+f] = 0.5*sum_e u[e][h][d][:]@Wm[e][:,h*64+f] - mean[h*64+f]
__global__ __launch_bounds__(256) void out_gemm_k(
    const float* __restrict__ u, const float* __restrict__ Wm,
    const float* __restrict__ mean, float* __restrict__ out) {
  __shared__ float As[16][132];
  __shared__ float Bs[16][68];
  const int h = blockIdx.y;
  const int tid = threadIdx.x;
  const int tx = tid & 15, ty = tid >> 4;
  const int row0 = blockIdx.x * 128;
  float acc[2][16] = {};
  for (int e = 0; e < 2; e++) {
    const float* Up = u + (size_t)(e * 4 + h) * NN * 64;
    const float* Wp = Wm + (size_t)e * 64 * 256 + h * 64;
    for (int k0 = 0; k0 < 64; k0 += 16) {
      #pragma unroll
      for (int i = 0; i < 2; i++) {
        int t = tid + i * 256;
        int r = t >> 2, cv = t & 3;
        int rr = row0 + r; if (rr >= NN) rr = NN - 1;
        float4 v = *(const float4*)(Up + (size_t)rr * 64 + k0 + cv * 4);
        As[cv*4+0][r] = v.x; As[cv*4+1][r] = v.y;
        As[cv*4+2][r] = v.z; As[cv*4+3][r] = v.w;
      }
      {
        int r = tid >> 4, c = tid & 15;
        *(float4*)&Bs[r][c*4] = *(const float4*)(Wp + (size_t)(k0 + r) * 256 + c * 4);
      }
      __syncthreads();
      #pragma unroll
      for (int kk = 0; kk < 16; kk++) {
        float4 a0 = *(const float4*)&As[kk][ty*4];
        float4 a1 = *(const float4*)&As[kk][64 + ty*4];
        float4 bv = *(const float4*)&Bs[kk][tx*4];
        float* ac = acc[0];
        ac[0]  += a0.x*bv.x; ac[1]  += a0.x*bv.y; ac[2]  += a0.x*bv.z; ac[3]  += a0.x*bv.w;
        ac[4]  += a0.y*bv.x; ac[5]  += a0.y*bv.y; ac[6]  += a0.y*bv.z; ac[7]  += a0.y*bv.w;
        ac[8]  += a0.z*bv.x; ac[9]  += a0.z*bv.y; ac[10] += a0.z*bv.z; ac[11] += a0.z*bv.w;
        ac[12] += a0.w*bv.x; ac[13] += a0.w*bv.y; ac[14] += a0.w*bv.z; ac[15] += a0.w*bv.w;
        ac = acc[1];
        ac[0]  += a1.x*bv.x; ac[1]  += a1.x*bv.y; ac[2]  += a1.x*bv.z; ac[3]  += a1.x*bv.w;
        ac[4]  += a1.y*bv.x; ac[5]  += a1.y*bv.y; ac[6]  += a1.y*bv.z; ac[7]  += a1.y*bv.w;
        ac[8]  += a1.z*bv.x; ac[9]  += a1.z*bv.y; ac[10] += a1.z*bv.z; ac[11] += a1.z*bv.w;
        ac[12] += a1.w*bv.x; ac[13] += a1.w*bv.y; ac[14] += a1.w*bv.z; ac[15] += a1.w*bv.w;
      }
      __syncthreads();
    }
  }
  float4 mn = *(const float4*)(mean + h * 64 + tx * 4);
  #pragma unroll
  for (int rp = 0; rp < 2; rp++) {
    #pragma unroll
    for (int i = 0; i < 4; i++) {
      int r = row0 + rp*64 + ty*4 + i;
      if (r < NN) {
        float* ac = acc[rp];
        *(float4*)(out + (size_t)r * 256 + h * 64 + tx * 4) =
            make_float4(0.5f*ac[i*4+0] - mn.x, 0.5f*ac[i*4+1] - mn.y,
                        0.5f*ac[i*4+2] - mn.z, 0.5f*ac[i*4+3] - mn.w);
      }
    }
  }
}

// ================= host-side launch =================
extern "C" void kernel_launch(void* const* d_in, const int* in_sizes, int n_in,
                              void* d_out, int out_size, void* d_ws, size_t ws_size,
                              hipStream_t stream) {
  const float* x    = (const float*)d_in[0];
  const int* src0 = (const int*)d_in[1];
  const int* dst0 = (const int*)d_in[2];
  const int* src1 = (const int*)d_in[3];
  const int* dst1 = (const int*)d_in[4];
  const float* W1  = (const float*)d_in[5];
  const float* al1 = (const float*)d_in[6];
  const float* ar1 = (const float*)d_in[7];
  const float* b1  = (const float*)d_in[8];
  const float* W2  = (const float*)d_in[9];
  const float* al2 = (const float*)d_in[10];
  const float* ar2 = (const float*)d_in[11];
  const float* b2  = (const float*)d_in[12];
  const float* Wm  = (const float*)d_in[13];
  const float* alm = (const float*)d_in[14];
  const float* arm = (const float*)d_in[15];
  // d_in[16] = bm: cancels under per-head mean-centering
  const float* fcw = (const float*)d_in[17];
  float* out = (float*)d_out;

  float* ws = (float*)d_ws;
  // zu region [0,25.6M): u1 (12.8M) in L1 phase, z2 (6.4M) in L2, u (25.6M) in MH
  float* zu     = ws;
  float* alpha1 = ws + 24000000;   // 1.6M; free zone during L1/L2 phases
  float* h1     = ws + 25600000;   // 6.4M; aliased as alpha4 in MH phase
  float* alpha4 = h1;
  float* h2     = ws + 32000000;   // 3.2M
  float* el     = ws + 35200000;   // 0.4M
  float* er     = ws + 35600000;   // 0.4M
  float* wl1    = ws + 36000000;   // 256
  float* wr1    = wl1 + 256;
  float* wl2    = wr1 + 256;
  float* wr2    = wl2 + 256;
  float* wlm    = wr2 + 256;       // 512
  float* wrm    = wlm + 512;       // 512
  float* usum   = wrm + 512;       // 512
  float* meanp  = usum + 512;      // 256
  int* rowptr  = (int*)(meanp + 256);          // 2*50001
  int* csr_src = rowptr + 100002;              // 2*EE
  // CSR build scratch aliases el/er/alpha1 (build precedes their first use)
  int* deg    = (int*)el;                      // 2*50000
  int* inc    = (int*)er;                      // 2*50000
  int* cursor = (int*)alpha1;                  // 2*50000
  int* bsum   = (int*)alpha1 + 100000;         // 2*128

  // ---- CSR build (merged across etypes) ----
  hipMemsetAsync(deg, 0, 2 * 50000 * sizeof(int), stream);
  hipMemsetAsync(cursor, 0, 2 * 50000 * sizeof(int), stream);
  hipMemsetAsync(usum, 0, 512 * sizeof(float), stream);
  deg2_k<<<6250, 256, 0, stream>>>(dst0, dst1, deg);
  scan1_k<<<dim3(98, 2), 512, 0, stream>>>(deg, inc, bsum);
  scan2_k<<<2, 128, 0, stream>>>(bsum, 98);
  scan3_k<<<dim3(196, 2), 256, 0, stream>>>(deg, inc, bsum, rowptr);
  csr_scatter2_k<<<6250, 256, 0, stream>>>(src0, dst0, src1, dst1,
                                           rowptr, cursor, csr_src);

  // ---- fold attention vectors through weights ----
  fold_k<<<8, 256, 0, stream>>>(W1, al1, ar1, W2, al2, ar2, Wm, alm, arm,
                                wl1, wr1, wl2, wr2, wlm, wrm);

  // ================= layer 1: gather x, then GEMM =================
  dot2_k<<<3125, 256, 0, stream>>>(x, wl1, wr1, el, er);
  alpha1_k<<<391, 256, 0, stream>>>(rowptr, csr_src, el, er, alpha1);
  agg_x_k<<<6250, 256, 0, stream>>>(rowptr, csr_src, alpha1, x, zu);
  ugemm1_k<<<391, 256, 0, stream>>>(zu, W1, b1, h1);

  // ================= layer 2: HID=128 -> OUT=64, fc agg =================
  dot2_k<<<3125, 256, 0, stream>>>(h1, wl2, wr2, el, er);
  gemm64_k<<<dim3(391, 1, 2), 256, 0, stream>>>(h1, W2, zu, NN, 128);
  alpha1_k<<<391, 256, 0, stream>>>(rowptr, csr_src, el, er, alpha1);
  agg2_k<<<3125, 256, 0, stream>>>(rowptr, csr_src, alpha1, zu, b2, fcw, h2);

  // ================= MH layer: gather h2, post-GEMM with Wm =================
  dotm_k<<<6250, 256, 0, stream>>>(h2, wlm, wrm, el, er);
  alpha4_k<<<391, 256, 0, stream>>>(rowptr, csr_src, el, er, alpha4);
  agg_mh_k<<<3125, 256, 0, stream>>>(rowptr, csr_src, alpha4, h2, zu);
  colsum_u_k<<<512, 256, 0, stream>>>(zu, usum);
  mean_k<<<1, 256, 0, stream>>>(usum, Wm, meanp);
  out_gemm_k<<<dim3(391, 4), 256, 0, stream>>>(zu, Wm, meanp, out);
}

// Round 8
// 729.263 us; speedup vs baseline: 14.6245x; 1.1582x over previous
//
#include <hip/hip_runtime.h>

#define NN 50000
#define EE 800000

// ---------------- bf16 helpers ----------------
__device__ inline unsigned int bf_pack(float lo, float hi) {
  unsigned int a = __float_as_uint(lo);
  a += 0x7FFFu + ((a >> 16) & 1u);
  unsigned int b = __float_as_uint(hi);
  b += 0x7FFFu + ((b >> 16) & 1u);
  return (a >> 16) | ((b >> 16) << 16);
}
__device__ inline void bf_dec8(uint4 v, float* f) {
  f[0] = __uint_as_float(v.x << 16); f[1] = __uint_as_float(v.x & 0xFFFF0000u);
  f[2] = __uint_as_float(v.y << 16); f[3] = __uint_as_float(v.y & 0xFFFF0000u);
  f[4] = __uint_as_float(v.z << 16); f[5] = __uint_as_float(v.z & 0xFFFF0000u);
  f[6] = __uint_as_float(v.w << 16); f[7] = __uint_as_float(v.w & 0xFFFF0000u);
}

// ================= CSR build =================
__global__ __launch_bounds__(256) void deg2_k(
    const int* __restrict__ dst0, const int* __restrict__ dst1,
    int* __restrict__ deg) {
  int i = blockIdx.x * 256 + threadIdx.x;
  if (i < EE) atomicAdd(&deg[dst0[i]], 1);
  else if (i < 2 * EE) atomicAdd(&deg[50000 + dst1[i - EE]], 1);
}

__global__ __launch_bounds__(512) void scan1_k(const int* __restrict__ deg,
                                               int* __restrict__ inc,
                                               int* __restrict__ bsum) {
  __shared__ int s[512];
  int e = blockIdx.y;
  int t = threadIdx.x, i = blockIdx.x * 512 + t;
  int v = (i < NN) ? deg[e * 50000 + i] : 0;
  s[t] = v; __syncthreads();
  #pragma unroll
  for (int off = 1; off < 512; off <<= 1) {
    int u = (t >= off) ? s[t - off] : 0;
    __syncthreads();
    s[t] += u;
    __syncthreads();
  }
  if (i < NN) inc[e * 50000 + i] = s[t];
  if (t == 511) bsum[e * 128 + blockIdx.x] = s[511];
}

__global__ __launch_bounds__(128) void scan2_k(int* __restrict__ bsum, int nb) {
  __shared__ int s[128];
  int e = blockIdx.x;
  int t = threadIdx.x;
  int v = (t < nb) ? bsum[e * 128 + t] : 0;
  s[t] = v; __syncthreads();
  #pragma unroll
  for (int off = 1; off < 128; off <<= 1) {
    int u = (t >= off) ? s[t - off] : 0;
    __syncthreads();
    s[t] += u;
    __syncthreads();
  }
  if (t < nb) bsum[e * 128 + t] = s[t] - v;
}

__global__ __launch_bounds__(256) void scan3_k(const int* __restrict__ deg,
                                               const int* __restrict__ inc,
                                               const int* __restrict__ bsum,
                                               int* __restrict__ rowptr) {
  int e = blockIdx.y;
  int i = blockIdx.x * 256 + threadIdx.x;
  if (i < NN)
    rowptr[e * 50001 + i] =
        inc[e * 50000 + i] - deg[e * 50000 + i] + bsum[e * 128 + (i >> 9)];
  if (i == NN) rowptr[e * 50001 + NN] = EE;
}

__global__ __launch_bounds__(256) void csr_scatter2_k(
    const int* __restrict__ src0, const int* __restrict__ dst0,
    const int* __restrict__ src1, const int* __restrict__ dst1,
    const int* __restrict__ rowptr, int* __restrict__ cursor,
    int* __restrict__ csr_src) {
  int i = blockIdx.x * 256 + threadIdx.x;
  if (i >= 2 * EE) return;
  int e = i >= EE;
  int k = i - e * EE;
  int d = e ? dst1[k] : dst0[k];
  int s = e ? src1[k] : src0[k];
  int pos = atomicAdd(&cursor[e * 50000 + d], 1);
  csr_src[(size_t)e * EE + rowptr[e * 50001 + d] + pos] = s;
}

// ======== fold a_l/a_r through weights ========
__global__ __launch_bounds__(256) void fold_k(
    const float* __restrict__ W1, const float* __restrict__ al1, const float* __restrict__ ar1,
    const float* __restrict__ W2, const float* __restrict__ al2, const float* __restrict__ ar2,
    const float* __restrict__ Wm, const float* __restrict__ alm, const float* __restrict__ arm,
    float* __restrict__ wl1, float* __restrict__ wr1,
    float* __restrict__ wl2, float* __restrict__ wr2,
    float* __restrict__ wlm, float* __restrict__ wrm) {
  int t = blockIdx.x * 256 + threadIdx.x;
  if (t < 512) {
    int lr = t >> 8, e = (t >> 7) & 1, k = t & 127;
    const float* a = (lr ? ar1 : al1) + e * 128;
    const float* w = W1 + ((size_t)e * 128 + k) * 128;
    float s = 0.f;
    for (int f = 0; f < 128; f++) s += w[f] * a[f];
    (lr ? wr1 : wl1)[e * 128 + k] = s;
  } else if (t < 1024) {
    int u = t - 512;
    int lr = u >> 8, e = (u >> 7) & 1, k = u & 127;
    const float* a = (lr ? ar2 : al2) + e * 64;
    const float* w = W2 + ((size_t)e * 128 + k) * 64;
    float s = 0.f;
    for (int f = 0; f < 64; f++) s += w[f] * a[f];
    (lr ? wr2 : wl2)[e * 128 + k] = s;
  } else if (t < 2048) {
    int u = t - 1024;
    int lr = u >> 9, e = (u >> 8) & 1, h = (u >> 6) & 3, k = u & 63;
    const float* a = (lr ? arm : alm) + (e * 4 + h) * 64;
    const float* w = Wm + ((size_t)e * 64 + k) * 256 + h * 64;
    float s = 0.f;
    for (int f = 0; f < 64; f++) s += w[f] * a[f];
    (lr ? wrm : wlm)[(e * 4 + h) * 64 + k] = s;
  }
}

// ======== cast x to bf16 ========
__global__ __launch_bounds__(256) void xcast_k(const float* __restrict__ x,
                                               unsigned int* __restrict__ xb) {
  int i = blockIdx.x * 256 + threadIdx.x;
  if (i >= NN * 64) return;
  float2 v = *(const float2*)(x + (size_t)i * 2);
  xb[i] = bf_pack(v.x, v.y);
}

// ================= el/er dots (fp32 features, K=128, both etypes) =============
__global__ __launch_bounds__(256) void dot2_k(
    const float* __restrict__ X, const float* __restrict__ wl,
    const float* __restrict__ wr, float* __restrict__ el, float* __restrict__ er) {
  int n = blockIdx.x * 16 + (threadIdx.x >> 4);
  int lane = threadIdx.x & 15;
  if (n >= NN) return;
  float p[4] = {0.f, 0.f, 0.f, 0.f};
  #pragma unroll
  for (int i = 0; i < 2; i++) {
    int c = (lane + i * 16) * 4;
    float4 xv = *(const float4*)(X + (size_t)n * 128 + c);
    #pragma unroll
    for (int e = 0; e < 2; e++) {
      float4 a = *(const float4*)(wl + e * 128 + c);
      float4 b = *(const float4*)(wr + e * 128 + c);
      p[e*2+0] += xv.x*a.x + xv.y*a.y + xv.z*a.z + xv.w*a.w;
      p[e*2+1] += xv.x*b.x + xv.y*b.y + xv.z*b.z + xv.w*b.w;
    }
  }
  #pragma unroll
  for (int off = 1; off < 16; off <<= 1) {
    #pragma unroll
    for (int i = 0; i < 4; i++) p[i] += __shfl_xor(p[i], off);
  }
  if (lane == 0) {
    el[n] = p[0]; er[n] = p[1];
    el[NN + n] = p[2]; er[NN + n] = p[3];
  }
}

// ===== layer1: fused alpha + gather of bf16 x; u1[e][d][128] =====
__global__ __launch_bounds__(256) void agg_x_f(
    const int* __restrict__ rowptr, const int* __restrict__ csr_src,
    const float* __restrict__ el, const float* __restrict__ er,
    const uint4* __restrict__ xb, float* __restrict__ u1) {
  int d = blockIdx.x * 16 + (threadIdx.x >> 4);
  int lane = threadIdx.x & 15;
  if (d >= NN) return;
  #pragma unroll
  for (int e = 0; e < 2; e++) {
    const int* rp = rowptr + e * 50001;
    const int* cs = csr_src + (size_t)e * EE;
    const float* elp = el + (size_t)e * NN;
    float erd = er[(size_t)e * NN + d];
    int j0 = rp[d], j1 = rp[d + 1];
    float sm = 0.f;
    for (int j = j0 + lane; j < j1; j += 16) {
      float v = elp[cs[j]] + erd; v = v >= 0.f ? v : 0.2f * v;
      sm += __expf(v);
    }
    #pragma unroll
    for (int off = 1; off < 16; off <<= 1) sm += __shfl_xor(sm, off, 16);
    float inv = 1.f / fmaxf(sm, 1e-9f);
    float acc[8] = {};
    int j = j0;
    for (; j + 4 <= j1; j += 4) {
      int s0 = cs[j], s1 = cs[j+1], s2 = cs[j+2], s3 = cs[j+3];
      float e0 = elp[s0] + erd; e0 = e0 >= 0.f ? e0 : 0.2f*e0;
      float e1 = elp[s1] + erd; e1 = e1 >= 0.f ? e1 : 0.2f*e1;
      float e2 = elp[s2] + erd; e2 = e2 >= 0.f ? e2 : 0.2f*e2;
      float e3 = elp[s3] + erd; e3 = e3 >= 0.f ? e3 : 0.2f*e3;
      uint4 v0 = xb[(size_t)s0 * 16 + lane];
      uint4 v1 = xb[(size_t)s1 * 16 + lane];
      uint4 v2 = xb[(size_t)s2 * 16 + lane];
      uint4 v3 = xb[(size_t)s3 * 16 + lane];
      float a0 = __expf(e0) * inv, a1 = __expf(e1) * inv;
      float a2 = __expf(e2) * inv, a3 = __expf(e3) * inv;
      float f0[8], f1[8], f2[8], f3[8];
      bf_dec8(v0, f0); bf_dec8(v1, f1); bf_dec8(v2, f2); bf_dec8(v3, f3);
      #pragma unroll
      for (int c = 0; c < 8; c++)
        acc[c] += a0*f0[c] + a1*f1[c] + a2*f2[c] + a3*f3[c];
    }
    for (; j < j1; j++) {
      int s = cs[j];
      float v = elp[s] + erd; v = v >= 0.f ? v : 0.2f*v;
      float a = __expf(v) * inv;
      uint4 vv = xb[(size_t)s * 16 + lane];
      float f[8]; bf_dec8(vv, f);
      #pragma unroll
      for (int c = 0; c < 8; c++) acc[c] += a * f[c];
    }
    float* up = u1 + ((size_t)e * NN + d) * 128 + lane * 8;
    *(float4*)up       = make_float4(acc[0], acc[1], acc[2], acc[3]);
    *(float4*)(up + 4) = make_float4(acc[4], acc[5], acc[6], acc[7]);
  }
}

// ===== h1 = 0.5*(u1[0]@W1[0] + u1[1]@W1[1]) + 0.5*(b1[0]+b1[1]) =====
__global__ __launch_bounds__(256) void ugemm1_k(
    const float* __restrict__ u1, const float* __restrict__ W1,
    const float* __restrict__ b1, float* __restrict__ h1) {
  __shared__ float As[16][132];
  __shared__ float Bs[16][132];
  const int tid = threadIdx.x;
  const int tx = tid & 15, ty = tid >> 4;
  const int row0 = blockIdx.x * 128;
  float acc[2][2][16] = {};
  for (int e = 0; e < 2; e++) {
    const float* Up = u1 + (size_t)e * NN * 128;
    const float* Wp = W1 + (size_t)e * 128 * 128;
    for (int k0 = 0; k0 < 128; k0 += 16) {
      #pragma unroll
      for (int i = 0; i < 2; i++) {
        int t = tid + i * 256;
        int r = t >> 2, cv = t & 3;
        int rr = row0 + r; if (rr >= NN) rr = NN - 1;
        float4 v = *(const float4*)(Up + (size_t)rr * 128 + k0 + cv * 4);
        As[cv*4+0][r] = v.x; As[cv*4+1][r] = v.y;
        As[cv*4+2][r] = v.z; As[cv*4+3][r] = v.w;
      }
      #pragma unroll
      for (int i = 0; i < 2; i++) {
        int t = tid + i * 256;
        int r = t >> 5, c = t & 31;
        *(float4*)&Bs[r][c*4] = *(const float4*)(Wp + (size_t)(k0 + r) * 128 + c * 4);
      }
      __syncthreads();
      #pragma unroll
      for (int kk = 0; kk < 16; kk++) {
        float4 a[2], b[2];
        a[0] = *(const float4*)&As[kk][ty*4];
        a[1] = *(const float4*)&As[kk][64 + ty*4];
        b[0] = *(const float4*)&Bs[kk][tx*4];
        b[1] = *(const float4*)&Bs[kk][64 + tx*4];
        #pragma unroll
        for (int rp = 0; rp < 2; rp++) {
          #pragma unroll
          for (int cp = 0; cp < 2; cp++) {
            float* ac = acc[rp][cp];
            float4 av = a[rp], bv = b[cp];
            ac[0]  += av.x*bv.x; ac[1]  += av.x*bv.y; ac[2]  += av.x*bv.z; ac[3]  += av.x*bv.w;
            ac[4]  += av.y*bv.x; ac[5]  += av.y*bv.y; ac[6]  += av.y*bv.z; ac[7]  += av.y*bv.w;
            ac[8]  += av.z*bv.x; ac[9]  += av.z*bv.y; ac[10] += av.z*bv.z; ac[11] += av.z*bv.w;
            ac[12] += av.w*bv.x; ac[13] += av.w*bv.y; ac[14] += av.w*bv.z; ac[15] += av.w*bv.w;
          }
        }
      }
      __syncthreads();
    }
  }
  #pragma unroll
  for (int rp = 0; rp < 2; rp++) {
    #pragma unroll
    for (int cp = 0; cp < 2; cp++) {
      int c = cp * 64 + tx * 4;
      float4 bb = make_float4(0.5f*(b1[c] + b1[128+c]),   0.5f*(b1[c+1] + b1[128+c+1]),
                              0.5f*(b1[c+2] + b1[128+c+2]), 0.5f*(b1[c+3] + b1[128+c+3]));
      #pragma unroll
      for (int i = 0; i < 4; i++) {
        int r = row0 + rp*64 + ty*4 + i;
        if (r < NN) {
          float* ac = acc[rp][cp];
          *(float4*)(h1 + (size_t)r * 128 + c) =
              make_float4(0.5f*ac[i*4+0] + bb.x, 0.5f*ac[i*4+1] + bb.y,
                          0.5f*ac[i*4+2] + bb.z, 0.5f*ac[i*4+3] + bb.w);
        }
      }
    }
  }
}

// ================= z2 (bf16) = h1 @ W2[e], 128x64 tiles ===================
__global__ __launch_bounds__(256) void gemm64_k(
    const float* __restrict__ X, const float* __restrict__ W,
    unsigned int* __restrict__ Zb) {
  __shared__ float As[16][132];
  __shared__ float Bs[16][68];
  const int e = blockIdx.z;
  const float* Wp = W + (size_t)e * 128 * 64;
  const int tid = threadIdx.x;
  const int tx = tid & 15, ty = tid >> 4;
  const int row0 = blockIdx.x * 128;
  float acc[2][16] = {};
  for (int k0 = 0; k0 < 128; k0 += 16) {
    #pragma unroll
    for (int i = 0; i < 2; i++) {
      int t = tid + i * 256;
      int r = t >> 2, cv = t & 3;
      int rr = row0 + r; if (rr >= NN) rr = NN - 1;
      float4 v = *(const float4*)(X + (size_t)rr * 128 + k0 + cv * 4);
      As[cv*4+0][r] = v.x; As[cv*4+1][r] = v.y;
      As[cv*4+2][r] = v.z; As[cv*4+3][r] = v.w;
    }
    {
      int r = tid >> 4, c = tid & 15;
      *(float4*)&Bs[r][c*4] = *(const float4*)(Wp + (size_t)(k0 + r) * 64 + c * 4);
    }
    __syncthreads();
    #pragma unroll
    for (int kk = 0; kk < 16; kk++) {
      float4 a0 = *(const float4*)&As[kk][ty*4];
      float4 a1 = *(const float4*)&As[kk][64 + ty*4];
      float4 bv = *(const float4*)&Bs[kk][tx*4];
      float* ac = acc[0];
      ac[0]  += a0.x*bv.x; ac[1]  += a0.x*bv.y; ac[2]  += a0.x*bv.z; ac[3]  += a0.x*bv.w;
      ac[4]  += a0.y*bv.x; ac[5]  += a0.y*bv.y; ac[6]  += a0.y*bv.z; ac[7]  += a0.y*bv.w;
      ac[8]  += a0.z*bv.x; ac[9]  += a0.z*bv.y; ac[10] += a0.z*bv.z; ac[11] += a0.z*bv.w;
      ac[12] += a0.w*bv.x; ac[13] += a0.w*bv.y; ac[14] += a0.w*bv.z; ac[15] += a0.w*bv.w;
      ac = acc[1];
      ac[0]  += a1.x*bv.x; ac[1]  += a1.x*bv.y; ac[2]  += a1.x*bv.z; ac[3]  += a1.x*bv.w;
      ac[4]  += a1.y*bv.x; ac[5]  += a1.y*bv.y; ac[6]  += a1.y*bv.z; ac[7]  += a1.y*bv.w;
      ac[8]  += a1.z*bv.x; ac[9]  += a1.z*bv.y; ac[10] += a1.z*bv.z; ac[11] += a1.z*bv.w;
      ac[12] += a1.w*bv.x; ac[13] += a1.w*bv.y; ac[14] += a1.w*bv.z; ac[15] += a1.w*bv.w;
    }
    __syncthreads();
  }
  #pragma unroll
  for (int rp = 0; rp < 2; rp++) {
    #pragma unroll
    for (int i = 0; i < 4; i++) {
      int r = row0 + rp*64 + ty*4 + i;
      if (r < NN) {
        float* ac = acc[rp];
        uint2 o;
        o.x = bf_pack(ac[i*4+0], ac[i*4+1]);
        o.y = bf_pack(ac[i*4+2], ac[i*4+3]);
        *(uint2*)(Zb + ((size_t)e * NN + r) * 32 + tx * 2) = o;
      }
    }
  }
}

// ===== layer2: fused alpha + gather bf16 z2 + fc/bias + bf16 h2 + MH dots =====
__global__ __launch_bounds__(256) void agg2_f(
    const int* __restrict__ rowptr, const int* __restrict__ csr_src,
    const float* __restrict__ el, const float* __restrict__ er,
    const uint4* __restrict__ zb, const float* __restrict__ bias,
    const float* __restrict__ fcw, const float* __restrict__ wlm,
    const float* __restrict__ wrm, uint4* __restrict__ h2b,
    float* __restrict__ elm, float* __restrict__ erm) {
  int d = blockIdx.x * 32 + (threadIdx.x >> 3);
  int lane = threadIdx.x & 7;
  if (d >= NN) return;
  int c0 = lane * 8;
  float coef0 = 0.5f * (fcw[0] + fcw[2]);
  float coef1 = 0.5f * (fcw[1] + fcw[3]);
  float hrow[8];
  #pragma unroll
  for (int c = 0; c < 8; c++)
    hrow[c] = coef0 * bias[c0 + c] + coef1 * bias[64 + c0 + c];
  #pragma unroll
  for (int e = 0; e < 2; e++) {
    const int* rp = rowptr + e * 50001;
    const int* cs = csr_src + (size_t)e * EE;
    const float* elp = el + (size_t)e * NN;
    float erd = er[(size_t)e * NN + d];
    const uint4* zp = zb + (size_t)e * NN * 8;
    int j0 = rp[d], j1 = rp[d + 1];
    float sm = 0.f;
    for (int j = j0 + lane; j < j1; j += 8) {
      float v = elp[cs[j]] + erd; v = v >= 0.f ? v : 0.2f * v;
      sm += __expf(v);
    }
    #pragma unroll
    for (int off = 1; off < 8; off <<= 1) sm += __shfl_xor(sm, off, 8);
    float cinv = (e ? coef1 : coef0) / fmaxf(sm, 1e-9f);
    float acc[8] = {};
    int j = j0;
    for (; j + 4 <= j1; j += 4) {
      int s0 = cs[j], s1 = cs[j+1], s2 = cs[j+2], s3 = cs[j+3];
      float e0 = elp[s0] + erd; e0 = e0 >= 0.f ? e0 : 0.2f*e0;
      float e1 = elp[s1] + erd; e1 = e1 >= 0.f ? e1 : 0.2f*e1;
      float e2 = elp[s2] + erd; e2 = e2 >= 0.f ? e2 : 0.2f*e2;
      float e3 = elp[s3] + erd; e3 = e3 >= 0.f ? e3 : 0.2f*e3;
      uint4 v0 = zp[(size_t)s0 * 8 + lane];
      uint4 v1 = zp[(size_t)s1 * 8 + lane];
      uint4 v2 = zp[(size_t)s2 * 8 + lane];
      uint4 v3 = zp[(size_t)s3 * 8 + lane];
      float a0 = __expf(e0), a1 = __expf(e1), a2 = __expf(e2), a3 = __expf(e3);
      float f0[8], f1[8], f2[8], f3[8];
      bf_dec8(v0, f0); bf_dec8(v1, f1); bf_dec8(v2, f2); bf_dec8(v3, f3);
      #pragma unroll
      for (int c = 0; c < 8; c++)
        acc[c] += a0*f0[c] + a1*f1[c] + a2*f2[c] + a3*f3[c];
    }
    for (; j < j1; j++) {
      int s = cs[j];
      float v = elp[s] + erd; v = v >= 0.f ? v : 0.2f*v;
      float a = __expf(v);
      uint4 vv = zp[(size_t)s * 8 + lane];
      float f[8]; bf_dec8(vv, f);
      #pragma unroll
      for (int c = 0; c < 8; c++) acc[c] += a * f[c];
    }
    #pragma unroll
    for (int c = 0; c < 8; c++) hrow[c] += cinv * acc[c];
  }
  uint4 o;
  o.x = bf_pack(hrow[0], hrow[1]); o.y = bf_pack(hrow[2], hrow[3]);
  o.z = bf_pack(hrow[4], hrow[5]); o.w = bf_pack(hrow[6], hrow[7]);
  h2b[(size_t)d * 8 + lane] = o;
  float p[16];
  #pragma unroll
  for (int e2 = 0; e2 < 2; e2++) {
    #pragma unroll
    for (int h = 0; h < 4; h++) {
      const float* a = wlm + (e2 * 4 + h) * 64 + c0;
      const float* b = wrm + (e2 * 4 + h) * 64 + c0;
      float sl = 0.f, sr = 0.f;
      #pragma unroll
      for (int c = 0; c < 8; c++) { sl += hrow[c] * a[c]; sr += hrow[c] * b[c]; }
      p[e2*4+h] = sl; p[8+e2*4+h] = sr;
    }
  }
  #pragma unroll
  for (int off = 1; off < 8; off <<= 1) {
    #pragma unroll
    for (int i = 0; i < 16; i++) p[i] += __shfl_xor(p[i], off, 8);
  }
  if (lane == 0) *(float4*)(elm + (size_t)d * 4)        = make_float4(p[0], p[1], p[2], p[3]);
  if (lane == 1) *(float4*)(elm + ((size_t)NN + d) * 4) = make_float4(p[4], p[5], p[6], p[7]);
  if (lane == 2) *(float4*)(erm + (size_t)d * 4)        = make_float4(p[8], p[9], p[10], p[11]);
  if (lane == 3) *(float4*)(erm + ((size_t)NN + d) * 4) = make_float4(p[12], p[13], p[14], p[15]);
}

// MH alpha: 4 heads, float4 alpha per edge
__global__ __launch_bounds__(256) void alpha4_k(
    const int* __restrict__ rowptr, const int* __restrict__ csr_src,
    const float* __restrict__ el, const float* __restrict__ er,
    float* __restrict__ alpha) {
  int t = blockIdx.x * 256 + threadIdx.x;
  if (t >= 2 * NN) return;
  int e = t / NN, d = t % NN;
  const int* rp = rowptr + e * 50001;
  const int* cs = csr_src + (size_t)e * EE;
  const float* elp = el + (size_t)e * NN * 4;
  float4 er4 = *(const float4*)(er + (size_t)t * 4);
  int j0 = rp[d], j1 = rp[d + 1];
  float4 sm = make_float4(0.f, 0.f, 0.f, 0.f);
  for (int j = j0; j < j1; j++) {
    float4 v = *(const float4*)(elp + (size_t)cs[j] * 4);
    v.x += er4.x; v.y += er4.y; v.z += er4.z; v.w += er4.w;
    v.x = v.x >= 0.f ? v.x : 0.2f*v.x; v.y = v.y >= 0.f ? v.y : 0.2f*v.y;
    v.z = v.z >= 0.f ? v.z : 0.2f*v.z; v.w = v.w >= 0.f ? v.w : 0.2f*v.w;
    sm.x += __expf(v.x); sm.y += __expf(v.y);
    sm.z += __expf(v.z); sm.w += __expf(v.w);
  }
  float4 inv = make_float4(1.f / fmaxf(sm.x, 1e-9f), 1.f / fmaxf(sm.y, 1e-9f),
                           1.f / fmaxf(sm.z, 1e-9f), 1.f / fmaxf(sm.w, 1e-9f));
  float* ap = alpha + (size_t)e * EE * 4;
  for (int j = j0; j < j1; j++) {
    float4 v = *(const float4*)(elp + (size_t)cs[j] * 4);
    v.x += er4.x; v.y += er4.y; v.z += er4.z; v.w += er4.w;
    v.x = v.x >= 0.f ? v.x : 0.2f*v.x; v.y = v.y >= 0.f ? v.y : 0.2f*v.y;
    v.z = v.z >= 0.f ? v.z : 0.2f*v.z; v.w = v.w >= 0.f ? v.w : 0.2f*v.w;
    *(float4*)(ap + (size_t)j * 4) =
        make_float4(__expf(v.x) * inv.x, __expf(v.y) * inv.y,
                    __expf(v.z) * inv.z, __expf(v.w) * inv.w);
  }
}

// u[(e*4+h)][d][0..63] = sum_j alpha4[e][j][h] * h2b[cs[j]]; 8 lanes per dst.
__global__ __launch_bounds__(256) void agg_mh_k(
    const int* __restrict__ rowptr, const int* __restrict__ csr_src,
    const float* __restrict__ alpha, const uint4* __restrict__ h2b,
    float* __restrict__ u) {
  int d = blockIdx.x * 32 + (threadIdx.x >> 3);
  int lane = threadIdx.x & 7, c0 = lane * 8;
  if (d >= NN) return;
  #pragma unroll
  for (int e = 0; e < 2; e++) {
    const int* rp = rowptr + e * 50001;
    const int* cs = csr_src + (size_t)e * EE;
    const float* ap = alpha + (size_t)e * EE * 4;
    float acc[4][8] = {};
    int j0 = rp[d], j1 = rp[d + 1];
    int j = j0;
    for (; j + 2 <= j1; j += 2) {
      int sA = cs[j], sB = cs[j+1];
      float4 wA = *(const float4*)(ap + (size_t)j * 4);
      float4 wB = *(const float4*)(ap + (size_t)(j+1) * 4);
      uint4 vA = h2b[(size_t)sA * 8 + lane];
      uint4 vB = h2b[(size_t)sB * 8 + lane];
      float fA[8], fB[8];
      bf_dec8(vA, fA); bf_dec8(vB, fB);
      #pragma unroll
      for (int c = 0; c < 8; c++) {
        acc[0][c] += wA.x*fA[c] + wB.x*fB[c];
        acc[1][c] += wA.y*fA[c] + wB.y*fB[c];
        acc[2][c] += wA.z*fA[c] + wB.z*fB[c];
        acc[3][c] += wA.w*fA[c] + wB.w*fB[c];
      }
    }
    for (; j < j1; j++) {
      int s = cs[j];
      float4 w = *(const float4*)(ap + (size_t)j * 4);
      uint4 vv = h2b[(size_t)s * 8 + lane];
      float f[8]; bf_dec8(vv, f);
      #pragma unroll
      for (int c = 0; c < 8; c++) {
        acc[0][c] += w.x*f[c]; acc[1][c] += w.y*f[c];
        acc[2][c] += w.z*f[c]; acc[3][c] += w.w*f[c];
      }
    }
    #pragma unroll
    for (int h = 0; h < 4; h++) {
      float* up = u + (((size_t)(e * 4 + h) * NN) + d) * 64 + c0;
      *(float4*)up       = make_float4(acc[h][0], acc[h][1], acc[h][2], acc[h][3]);
      *(float4*)(up + 4) = make_float4(acc[h][4], acc[h][5], acc[h][6], acc[h][7]);
    }
  }
}

// ===== column sums of u per (e,h) =====
__global__ __launch_bounds__(256) void colsum_u_k(
    const float* __restrict__ u, float* __restrict__ usum) {
  __shared__ float lds[4][64];
  int eh = blockIdx.x >> 6;
  int chunk = blockIdx.x & 63;
  int c = threadIdx.x & 63, rg = threadIdx.x >> 6;
  const float* up = u + (size_t)eh * NN * 64;
  int n0 = chunk * 782;
  int n1 = n0 + 782; if (n1 > NN) n1 = NN;
  float s = 0.f;
  for (int n = n0 + rg; n < n1; n += 4) s += up[(size_t)n * 64 + c];
  lds[rg][c] = s;
  __syncthreads();
  if (rg == 0) {
    float t = lds[0][c] + lds[1][c] + lds[2][c] + lds[3][c];
    unsafeAtomicAdd(&usum[eh * 64 + c], t);
  }
}

__global__ __launch_bounds__(256) void mean_k(
    const float* __restrict__ usum, const float* __restrict__ Wm,
    float* __restrict__ mean) {
  int c = threadIdx.x;
  int h = c >> 6;
  float s = 0.f;
  for (int e = 0; e < 2; e++) {
    const float* us = usum + (e * 4 + h) * 64;
    const float* wp = Wm + (size_t)e * 64 * 256 + c;
    for (int k = 0; k < 64; k++) s += us[k] * wp[(size_t)k * 256];
  }
  mean[c] = s * (0.5f / NN);
}

// out[d][h*64+f] = 0.5*sum_e u[(e*4+h)][d][:]@Wm[e][:,h*64+f] - mean[c]
__global__ __launch_bounds__(256) void out_gemm_k(
    const float* __restrict__ u, const float* __restrict__ Wm,
    const float* __restrict__ mean, float* __restrict__ out) {
  __shared__ float As[16][132];
  __shared__ float Bs[16][68];
  const int h = blockIdx.y;
  const int tid = threadIdx.x;
  const int tx = tid & 15, ty = tid >> 4;
  const int row0 = blockIdx.x * 128;
  float acc[2][16] = {};
  for (int e = 0; e < 2; e++) {
    const float* Up = u + (size_t)(e * 4 + h) * NN * 64;
    const float* Wp = Wm + (size_t)e * 64 * 256 + h * 64;
    for (int k0 = 0; k0 < 64; k0 += 16) {
      #pragma unroll
      for (int i = 0; i < 2; i++) {
        int t = tid + i * 256;
        int r = t >> 2, cv = t & 3;
        int rr = row0 + r; if (rr >= NN) rr = NN - 1;
        float4 v = *(const float4*)(Up + (size_t)rr * 64 + k0 + cv * 4);
        As[cv*4+0][r] = v.x; As[cv*4+1][r] = v.y;
        As[cv*4+2][r] = v.z; As[cv*4+3][r] = v.w;
      }
      {
        int r = tid >> 4, c = tid & 15;
        *(float4*)&Bs[r][c*4] = *(const float4*)(Wp + (size_t)(k0 + r) * 256 + c * 4);
      }
      __syncthreads();
      #pragma unroll
      for (int kk = 0; kk < 16; kk++) {
        float4 a0 = *(const float4*)&As[kk][ty*4];
        float4 a1 = *(const float4*)&As[kk][64 + ty*4];
        float4 bv = *(const float4*)&Bs[kk][tx*4];
        float* ac = acc[0];
        ac[0]  += a0.x*bv.x; ac[1]  += a0.x*bv.y; ac[2]  += a0.x*bv.z; ac[3]  += a0.x*bv.w;
        ac[4]  += a0.y*bv.x; ac[5]  += a0.y*bv.y; ac[6]  += a0.y*bv.z; ac[7]  += a0.y*bv.w;
        ac[8]  += a0.z*bv.x; ac[9]  += a0.z*bv.y; ac[10] += a0.z*bv.z; ac[11] += a0.z*bv.w;
        ac[12] += a0.w*bv.x; ac[13] += a0.w*bv.y; ac[14] += a0.w*bv.z; ac[15] += a0.w*bv.w;
        ac = acc[1];
        ac[0]  += a1.x*bv.x; ac[1]  += a1.x*bv.y; ac[2]  += a1.x*bv.z; ac[3]  += a1.x*bv.w;
        ac[4]  += a1.y*bv.x; ac[5]  += a1.y*bv.y; ac[6]  += a1.y*bv.z; ac[7]  += a1.y*bv.w;
        ac[8]  += a1.z*bv.x; ac[9]  += a1.z*bv.y; ac[10] += a1.z*bv.z; ac[11] += a1.z*bv.w;
        ac[12] += a1.w*bv.x; ac[13] += a1.w*bv.y; ac[14] += a1.w*bv.z; ac[15] += a1.w*bv.w;
      }
      __syncthreads();
    }
  }
  float4 mn = *(const float4*)(mean + h * 64 + tx * 4);
  #pragma unroll
  for (int rp = 0; rp < 2; rp++) {
    #pragma unroll
    for (int i = 0; i < 4; i++) {
      int r = row0 + rp*64 + ty*4 + i;
      if (r < NN) {
        float* ac = acc[rp];
        *(float4*)(out + (size_t)r * 256 + h * 64 + tx * 4) =
            make_float4(0.5f*ac[i*4+0] - mn.x, 0.5f*ac[i*4+1] - mn.y,
                        0.5f*ac[i*4+2] - mn.z, 0.5f*ac[i*4+3] - mn.w);
      }
    }
  }
}

// ================= host-side launch =================
extern "C" void kernel_launch(void* const* d_in, const int* in_sizes, int n_in,
                              void* d_out, int out_size, void* d_ws, size_t ws_size,
                              hipStream_t stream) {
  const float* x  = (const float*)d_in[0];
  const int* src0 = (const int*)d_in[1];
  const int* dst0 = (const int*)d_in[2];
  const int* src1 = (const int*)d_in[3];
  const int* dst1 = (const int*)d_in[4];
  const float* W1  = (const float*)d_in[5];
  const float* al1 = (const float*)d_in[6];
  const float* ar1 = (const float*)d_in[7];
  const float* b1  = (const float*)d_in[8];
  const float* W2  = (const float*)d_in[9];
  const float* al2 = (const float*)d_in[10];
  const float* ar2 = (const float*)d_in[11];
  const float* b2  = (const float*)d_in[12];
  const float* Wm  = (const float*)d_in[13];
  const float* alm = (const float*)d_in[14];
  const float* arm = (const float*)d_in[15];
  // d_in[16] = bm: cancels under per-head mean-centering
  const float* fcw = (const float*)d_in[17];
  float* out = (float*)d_out;

  float* ws = (float*)d_ws;
  float* zu     = ws;                                  // u1 fp32 12.8M / u 25.6M
  unsigned int* z2b = (unsigned int*)(ws + 12800000);  // bf16 z2, 3.2M uints
  float* h1     = ws + 25600000;   // 6.4M; aliases xb early, alpha4 late
  unsigned int* xb = (unsigned int*)h1;
  float* alpha4 = h1;
  unsigned int* h2b = (unsigned int*)(ws + 32000000);  // 1.6M uints
  float* el     = ws + 33600000;   // 0.4M
  float* er     = ws + 34000000;   // 0.4M
  float* elm    = ws + 34400000;   // 0.4M
  float* erm    = ws + 34800000;   // 0.4M
  float* wl1    = ws + 35200000;
  float* wr1    = wl1 + 256;
  float* wl2    = wr1 + 256;
  float* wr2    = wl2 + 256;
  float* wlm    = wr2 + 256;
  float* wrm    = wlm + 512;
  float* usum   = wrm + 512;
  float* meanp  = usum + 512;
  int* rowptr  = (int*)(meanp + 256);          // 2*50001
  int* csr_src = rowptr + 100002;              // 2*EE
  int* deg    = (int*)el;
  int* inc    = (int*)er;
  int* cursor = (int*)zu;
  int* bsum   = (int*)zu + 200000;

  hipMemsetAsync(deg, 0, 2 * 50000 * sizeof(int), stream);
  hipMemsetAsync(cursor, 0, 2 * 50000 * sizeof(int), stream);
  hipMemsetAsync(usum, 0, 512 * sizeof(float), stream);
  deg2_k<<<6250, 256, 0, stream>>>(dst0, dst1, deg);
  scan1_k<<<dim3(98, 2), 512, 0, stream>>>(deg, inc, bsum);
  scan2_k<<<2, 128, 0, stream>>>(bsum, 98);
  scan3_k<<<dim3(196, 2), 256, 0, stream>>>(deg, inc, bsum, rowptr);
  csr_scatter2_k<<<6250, 256, 0, stream>>>(src0, dst0, src1, dst1,
                                           rowptr, cursor, csr_src);

  fold_k<<<8, 256, 0, stream>>>(W1, al1, ar1, W2, al2, ar2, Wm, alm, arm,
                                wl1, wr1, wl2, wr2, wlm, wrm);
  xcast_k<<<12500, 256, 0, stream>>>(x, xb);

  // ================= layer 1 =================
  dot2_k<<<3125, 256, 0, stream>>>(x, wl1, wr1, el, er);
  agg_x_f<<<3125, 256, 0, stream>>>(rowptr, csr_src, el, er, (const uint4*)xb, zu);
  ugemm1_k<<<391, 256, 0, stream>>>(zu, W1, b1, h1);

  // ================= layer 2 =================
  dot2_k<<<3125, 256, 0, stream>>>(h1, wl2, wr2, el, er);
  gemm64_k<<<dim3(391, 1, 2), 256, 0, stream>>>(h1, W2, z2b);
  agg2_f<<<1563, 256, 0, stream>>>(rowptr, csr_src, el, er, (const uint4*)z2b,
                                   b2, fcw, wlm, wrm, (uint4*)h2b, elm, erm);

  // ================= MH layer =================
  alpha4_k<<<391, 256, 0, stream>>>(rowptr, csr_src, elm, erm, alpha4);
  agg_mh_k<<<1563, 256, 0, stream>>>(rowptr, csr_src, alpha4, (const uint4*)h2b, zu);
  colsum_u_k<<<512, 256, 0, stream>>>(zu, usum);
  mean_k<<<1, 256, 0, stream>>>(usum, Wm, meanp);
  out_gemm_k<<<dim3(391, 4), 256, 0, stream>>>(zu, Wm, meanp, out);
}